// Round 2
// baseline (324.405 us; speedup 1.0000x reference)
//
#include <hip/hip_runtime.h>

typedef __attribute__((ext_vector_type(8))) __bf16 bf16x8;
typedef __attribute__((ext_vector_type(4))) float f32x4;

#define MAX_ITER_N 20
#define F_TOL_F 1e-6f
#define FREE_NUM_N 64

#define BSZ 1024
#define IN_DIM 512
#define HID 1024
#define OUT_DIM 256
#define M_CON 128

// workspace layout (float offsets); ctrl region [0..48) zeroed by memset each call
#define WS_DONE  0                         // uint: loop-stage completion counter
#define WS_GCNT  1                         // uint: monotonic grid-barrier counter
#define WS_RES   8                         // 32 uints: per-iter residuals
#define WS_BP    48                        // 256 f32: bias_proj
#define WS_H1    304
#define WS_H2    (WS_H1 + 524288)
#define WS_APC   (WS_H2 + 524288)
#define WS_W0C   (WS_APC + 262144)
#define WS_W1C   (WS_W0C + 262144)
#define WS_W2C   (WS_W1C + 524288)
#define WS_WZG   (WS_W2C + 131072)
#define WS_AG    (WS_WZG + 32768)

__device__ __forceinline__ unsigned short f2bf(float f) {
    unsigned int u = __float_as_uint(f);
    u += 0x7fffu + ((u >> 16) & 1u);
    return (unsigned short)(u >> 16);
}

__device__ __forceinline__ void gload_lds16(const unsigned short* g, unsigned short* l) {
    __builtin_amdgcn_global_load_lds(
        (const __attribute__((address_space(1))) unsigned int*)(const void*)g,
        (__attribute__((address_space(3))) unsigned int*)(void*)l, 16, 0, 0);
}

// fragment read from a Nx128 bf16 tile with 4-bit XOR granule swizzle
__device__ __forceinline__ bf16x8 frag128(const unsigned short* lds, int row, int gc) {
    int phys = gc ^ (row & 15);
    return __builtin_bit_cast(bf16x8, *(const uint4*)(lds + row * 128 + phys * 8));
}

// monotonic grid barrier: all 256 blocks co-resident (1 blk/CU guaranteed:
// 64KiB LDS < 160, <=512 VGPR). gcnt zeroed by stream memset each call.
__device__ __forceinline__ void gbar(unsigned int* gcnt, unsigned int target) {
    __syncthreads();
    __threadfence();                       // release: drain + L2 writeback
    if (threadIdx.x == 0) {
        atomicAdd(gcnt, 1u);
        while (__hip_atomic_load(gcnt, __ATOMIC_RELAXED, __HIP_MEMORY_SCOPE_AGENT) < target)
            __builtin_amdgcn_s_sleep(1);
    }
    __syncthreads();
    __threadfence();                       // acquire: invalidate caches
}

// ---- 64x64-tile MFMA GEMM stage, BK=128, double-buffered LDS ----
template<int K, bool RELU, bool F32OUT>
__device__ __forceinline__ void gemm64_dev(
    const unsigned short* __restrict__ A, const unsigned short* __restrict__ B,
    const float* __restrict__ bias, void* __restrict__ Cv, int N_,
    int row0, int col0, unsigned short* sA, unsigned short* sB)
{
    constexpr int NCH = K / 128;
    const int tid = threadIdx.x;
    const int w = tid >> 6;
    const int lane = tid & 63;
    const int ln = lane & 15;
    const int q  = lane >> 4;
    const int wr = w >> 1;
    const int wc = w & 1;
    const unsigned short* Ab = A + row0 * K;
    const unsigned short* Bb = B + col0 * K;

    int soff[4], dbase[4];
#pragma unroll
    for (int i = 0; i < 4; ++i) {
        int P = w * 256 + i * 64 + lane;               // LDS granule (lane-linear)
        int row = P >> 4, pgc = P & 15;
        soff[i]  = row * K + (pgc ^ (row & 15)) * 8;   // XOR-permuted global source
        dbase[i] = (w * 256 + i * 64) * 8;             // shorts (wave-uniform base)
    }

    f32x4 acc[2][2];
#pragma unroll
    for (int rm = 0; rm < 2; ++rm)
#pragma unroll
        for (int cn = 0; cn < 2; ++cn)
            acc[rm][cn] = (f32x4){0.f, 0.f, 0.f, 0.f};

#pragma unroll
    for (int i = 0; i < 4; ++i) {
        gload_lds16(Ab + soff[i], sA + dbase[i]);
        gload_lds16(Bb + soff[i], sB + dbase[i]);
    }

    for (int c = 0; c < NCH; ++c) {
        __syncthreads();
        if (c + 1 < NCH) {
            const unsigned short* Ak = Ab + (c + 1) * 128;
            const unsigned short* Bk = Bb + (c + 1) * 128;
            int nb = ((c + 1) & 1) * 8192;
#pragma unroll
            for (int i = 0; i < 4; ++i) {
                gload_lds16(Ak + soff[i], sA + nb + dbase[i]);
                gload_lds16(Bk + soff[i], sB + nb + dbase[i]);
            }
        }
        const unsigned short* Ac = sA + (c & 1) * 8192;
        const unsigned short* Bc = sB + (c & 1) * 8192;
#pragma unroll
        for (int ks = 0; ks < 4; ++ks) {
            bf16x8 af0 = frag128(Ac, wr * 32 + ln,      ks * 4 + q);
            bf16x8 af1 = frag128(Ac, wr * 32 + 16 + ln, ks * 4 + q);
            bf16x8 bf0 = frag128(Bc, wc * 32 + ln,      ks * 4 + q);
            bf16x8 bf1 = frag128(Bc, wc * 32 + 16 + ln, ks * 4 + q);
            acc[0][0] = __builtin_amdgcn_mfma_f32_16x16x32_bf16(af0, bf0, acc[0][0], 0, 0, 0);
            acc[0][1] = __builtin_amdgcn_mfma_f32_16x16x32_bf16(af0, bf1, acc[0][1], 0, 0, 0);
            acc[1][0] = __builtin_amdgcn_mfma_f32_16x16x32_bf16(af1, bf0, acc[1][0], 0, 0, 0);
            acc[1][1] = __builtin_amdgcn_mfma_f32_16x16x32_bf16(af1, bf1, acc[1][1], 0, 0, 0);
        }
    }

#pragma unroll
    for (int cn = 0; cn < 2; ++cn) {
        const int cc = col0 + wc * 32 + cn * 16 + ln;
        const float bv = bias[cc];
#pragma unroll
        for (int rm = 0; rm < 2; ++rm)
#pragma unroll
            for (int i = 0; i < 4; ++i) {
                int r = row0 + wr * 32 + rm * 16 + q * 4 + i;
                float v = acc[rm][cn][i] + bv;
                if (RELU) v = fmaxf(v, 0.0f);
                if (F32OUT) ((float*)Cv)[r * N_ + cc] = v;
                else ((unsigned short*)Cv)[r * N_ + cc] = f2bf(v);
            }
    }
}

// ---- 32x32-tile GEMM stage (gemm3: all 256 blocks active) ----
template<int K, bool RELU, bool F32OUT>
__device__ __forceinline__ void gemm32_dev(
    const unsigned short* __restrict__ A, const unsigned short* __restrict__ B,
    const float* __restrict__ bias, void* __restrict__ Cv, int N_,
    int row0, int col0, unsigned short* sA, unsigned short* sB)
{
    constexpr int NCH = K / 128;
    const int tid = threadIdx.x;
    const int w = tid >> 6;
    const int lane = tid & 63;
    const int ln = lane & 15;
    const int q  = lane >> 4;
    const int wr = w >> 1;
    const int wc = w & 1;
    const unsigned short* Ab = A + row0 * K;
    const unsigned short* Bb = B + col0 * K;

    int soff[2], dbase[2];
#pragma unroll
    for (int i = 0; i < 2; ++i) {
        int P = w * 128 + i * 64 + lane;
        int row = P >> 4, pgc = P & 15;
        soff[i]  = row * K + (pgc ^ (row & 15)) * 8;
        dbase[i] = (w * 128 + i * 64) * 8;
    }

    f32x4 acc = {0.f, 0.f, 0.f, 0.f};

#pragma unroll
    for (int i = 0; i < 2; ++i) {
        gload_lds16(Ab + soff[i], sA + dbase[i]);
        gload_lds16(Bb + soff[i], sB + dbase[i]);
    }

    for (int c = 0; c < NCH; ++c) {
        __syncthreads();
        if (c + 1 < NCH) {
            const unsigned short* Ak = Ab + (c + 1) * 128;
            const unsigned short* Bk = Bb + (c + 1) * 128;
            int nb = ((c + 1) & 1) * 4096;
#pragma unroll
            for (int i = 0; i < 2; ++i) {
                gload_lds16(Ak + soff[i], sA + nb + dbase[i]);
                gload_lds16(Bk + soff[i], sB + nb + dbase[i]);
            }
        }
        const unsigned short* Ac = sA + (c & 1) * 4096;
        const unsigned short* Bc = sB + (c & 1) * 4096;
#pragma unroll
        for (int ks = 0; ks < 4; ++ks) {
            bf16x8 af = frag128(Ac, wr * 16 + ln, ks * 4 + q);
            bf16x8 bf = frag128(Bc, wc * 16 + ln, ks * 4 + q);
            acc = __builtin_amdgcn_mfma_f32_16x16x32_bf16(af, bf, acc, 0, 0, 0);
        }
    }

    const int cc = col0 + wc * 16 + ln;
    const float bv = bias[cc];
#pragma unroll
    for (int i = 0; i < 4; ++i) {
        int r = row0 + wr * 16 + q * 4 + i;
        float v = acc[i] + bv;
        if (RELU) v = fmaxf(v, 0.0f);
        if (F32OUT) ((float*)Cv)[r * N_ + cc] = v;
        else ((unsigned short*)Cv)[r * N_ + cc] = f2bf(v);
    }
}

// ---- single fused kernel: prep | gemm1 | gemm2 | gemm3 | loop+decide ----
__global__ __launch_bounds__(256, 1) void fused_k(
    const float* __restrict__ b_primal, const float* __restrict__ W0,
    const float* __restrict__ b0v, const float* __restrict__ W1,
    const float* __restrict__ b1v, const float* __restrict__ W2,
    const float* __restrict__ b2v, const float* __restrict__ Am,
    const float* __restrict__ b_vec, const float* __restrict__ WzProj,
    const float* __restrict__ WbProj,
    float* __restrict__ out, float* __restrict__ ws)
{
    __shared__ __align__(16) unsigned char smem[65536];

    unsigned int* done = (unsigned int*)ws + WS_DONE;
    unsigned int* gcnt = (unsigned int*)ws + WS_GCNT;
    unsigned int* res  = (unsigned int*)(ws + WS_RES);
    float* bp = ws + WS_BP;
    unsigned short* h1c = (unsigned short*)(ws + WS_H1);
    unsigned short* h2c = (unsigned short*)(ws + WS_H2);
    unsigned short* APc = (unsigned short*)(ws + WS_APC);
    unsigned short* W0c = (unsigned short*)(ws + WS_W0C);
    unsigned short* W1c = (unsigned short*)(ws + WS_W1C);
    unsigned short* W2c = (unsigned short*)(ws + WS_W2C);
    unsigned short* WzG = (unsigned short*)(ws + WS_WZG);
    unsigned short* AG  = (unsigned short*)(ws + WS_AG);
    float* outz = out + BSZ * OUT_DIM;

    const int tid = threadIdx.x;
    const int bid = blockIdx.x;

    unsigned short* sA = (unsigned short*)smem;            // gemm64: [2][8192]; gemm32: [2][4096]
    unsigned short* sB = (unsigned short*)(smem + 32768);

    // ---- stage 0: bf16 conversions + bias_proj ----
    for (int u = bid; u < 2400; u += 256) {
        const float* src; unsigned short* dst; int off;
        if (u < 512)       { src = b_primal; dst = APc; off = u; }
        else if (u < 1024) { src = W0;     dst = W0c; off = u - 512; }
        else if (u < 2048) { src = W1;     dst = W1c; off = u - 1024; }
        else if (u < 2304) { src = W2;     dst = W2c; off = u - 2048; }
        else if (u < 2368) { src = WzProj; dst = WzG; off = u - 2304; }
        else               { src = Am;     dst = AG;  off = u - 2368; }
        int idx = off * 1024 + tid * 4;
        float4 v = *(const float4*)(src + idx);
        ushort4 o;
        o.x = f2bf(v.x); o.y = f2bf(v.y); o.z = f2bf(v.z); o.w = f2bf(v.w);
        *(ushort4*)(dst + idx) = o;
    }
    if (bid == 0) {
        float s = 0.0f;
        for (int k = 0; k < M_CON; ++k) s += b_vec[k] * WbProj[tid * M_CON + k];
        bp[tid] = s;
    }
    gbar(gcnt, 256);

    // ---- stage 1: h1 = relu(x @ W0^T + b0), 16x16 tiles of 64x64 ----
    gemm64_dev<IN_DIM, true, false>(APc, W0c, b0v, (void*)h1c, HID,
                                    (bid >> 4) * 64, (bid & 15) * 64, sA, sB);
    gbar(gcnt, 512);

    // ---- stage 2: h2 = relu(h1 @ W1^T + b1) ----
    gemm64_dev<HID, true, false>(h1c, W1c, b1v, (void*)h2c, HID,
                                 (bid >> 4) * 64, (bid & 15) * 64, sA, sB);
    gbar(gcnt, 768);

    // ---- stage 3: out0 = h2 @ W2^T + b2 (f32), 32x8 tiles of 32x32 ----
    gemm32_dev<HID, false, true>(h2c, W2c, b2v, (void*)outz, OUT_DIM,
                                 (bid >> 3) * 32, (bid & 7) * 32, sA, sB);
    gbar(gcnt, 1024);

    if (bid >= 64) return;

    // ---- stage 4: 20-iter fixed-point loop + fused residual + decide ----
    const int wave = tid >> 6;
    const int lane = tid & 63;
    const int ln   = lane & 15;
    const int q    = lane >> 4;
    const int r0   = bid * 16;

    unsigned short (*zS)[264] = (unsigned short(*)[264])smem;
    float* red = (float*)(smem + 60928);

    {   // stage z0 = outz rows into zS as bf16
        int row = tid >> 4;
        int c0  = (tid & 15) * 16;
        const float* src = outz + (r0 + row) * OUT_DIM + c0;
#pragma unroll
        for (int i = 0; i < 4; ++i) {
            float4 v = *(const float4*)(src + i * 4);
            ushort4 o;
            o.x = f2bf(v.x); o.y = f2bf(v.y); o.z = f2bf(v.z); o.w = f2bf(v.w);
            *(ushort4*)&zS[row][c0 + i * 4] = o;
        }
    }

    bf16x8 afr[2][8];
    float bvv[2];
#pragma unroll
    for (int mt = 0; mt < 2; ++mt) {
        int m = wave * 32 + mt * 16 + ln;
        bvv[mt] = b_vec[m];
#pragma unroll
        for (int ks = 0; ks < 8; ++ks)
            afr[mt][ks] = __builtin_bit_cast(bf16x8, *(const uint4*)(AG + m * OUT_DIM + ks * 32 + q * 8));
    }
    int colg[4];
    float bpv[4];
    bf16x8 wzfr[4][8];
#pragma unroll
    for (int nt = 0; nt < 4; ++nt) {
        colg[nt] = wave * 64 + nt * 16 + ln;
        bpv[nt]  = bp[colg[nt]];
#pragma unroll
        for (int ks = 0; ks < 8; ++ks)
            wzfr[nt][ks] = __builtin_bit_cast(bf16x8, *(const uint4*)(WzG + colg[nt] * OUT_DIM + ks * 32 + q * 8));
    }
    __syncthreads();

    bf16x8 zfr[8];
#pragma unroll
    for (int ks = 0; ks < 8; ++ks)
        zfr[ks] = __builtin_bit_cast(bf16x8, *(const uint4*)&zS[ln][ks * 32 + q * 8]);

    const f32x4 zero4 = {0.f, 0.f, 0.f, 0.f};

    for (int t = 1; t <= MAX_ITER_N; ++t) {
        f32x4 acc[4];
        f32x4 acc2[2];
#pragma unroll
        for (int nt = 0; nt < 4; ++nt) acc[nt] = zero4;
        acc2[0] = zero4; acc2[1] = zero4;
#pragma unroll
        for (int ks = 0; ks < 8; ++ks) {
#pragma unroll
            for (int nt = 0; nt < 4; ++nt)
                acc[nt] = __builtin_amdgcn_mfma_f32_16x16x32_bf16(zfr[ks], wzfr[nt][ks], acc[nt], 0, 0, 0);
            if (t > 1) {
#pragma unroll
                for (int mt = 0; mt < 2; ++mt)
                    acc2[mt] = __builtin_amdgcn_mfma_f32_16x16x32_bf16(zfr[ks], afr[mt][ks], acc2[mt], 0, 0, 0);
            }
        }
        float vals[4][4];
#pragma unroll
        for (int nt = 0; nt < 4; ++nt)
#pragma unroll
            for (int i = 0; i < 4; ++i) {
                float v = acc[nt][i] + bpv[nt];
                if (colg[nt] >= FREE_NUM_N) v = fmaxf(v, 0.0f);
                vals[nt][i] = v;
            }
        if (t > 1) {   // residual of z_{t-1} -> res[t-2]
            float lmax = 0.0f;
#pragma unroll
            for (int mt = 0; mt < 2; ++mt)
#pragma unroll
                for (int i = 0; i < 4; ++i)
                    lmax = fmaxf(lmax, fabsf(acc2[mt][i] - bvv[mt]));
#pragma unroll
            for (int off = 32; off > 0; off >>= 1)
                lmax = fmaxf(lmax, __shfl_xor(lmax, off));
            if (lane == 0) red[wave] = lmax;
        }
        if (t == MAX_ITER_N) {
#pragma unroll
            for (int nt = 0; nt < 4; ++nt)
#pragma unroll
                for (int i = 0; i < 4; ++i)
                    out[(r0 + q * 4 + i) * OUT_DIM + colg[nt]] = vals[nt][i];
        }
        __syncthreads();   // S1: reads of zS done + red written
        if (t > 1 && tid == 0) {
            float bm = fmaxf(fmaxf(red[0], red[1]), fmaxf(red[2], red[3]));
            atomicMax(res + (t - 2), __float_as_uint(bm));
        }
#pragma unroll
        for (int nt = 0; nt < 4; ++nt)
#pragma unroll
            for (int i = 0; i < 4; ++i)
                zS[q * 4 + i][colg[nt]] = f2bf(vals[nt][i]);
        __syncthreads();   // S2: zS = z_t complete
#pragma unroll
        for (int ks = 0; ks < 8; ++ks)
            zfr[ks] = __builtin_bit_cast(bf16x8, *(const uint4*)&zS[ln][ks * 32 + q * 8]);
    }

    {   // final residual of z_20 -> res[19], then 64-block completion
        f32x4 acc2[2];
        acc2[0] = zero4; acc2[1] = zero4;
#pragma unroll
        for (int ks = 0; ks < 8; ++ks)
#pragma unroll
            for (int mt = 0; mt < 2; ++mt)
                acc2[mt] = __builtin_amdgcn_mfma_f32_16x16x32_bf16(zfr[ks], afr[mt][ks], acc2[mt], 0, 0, 0);
        float lmax = 0.0f;
#pragma unroll
        for (int mt = 0; mt < 2; ++mt)
#pragma unroll
            for (int i = 0; i < 4; ++i)
                lmax = fmaxf(lmax, fabsf(acc2[mt][i] - bvv[mt]));
#pragma unroll
        for (int off = 32; off > 0; off >>= 1)
            lmax = fmaxf(lmax, __shfl_xor(lmax, off));
        if (lane == 0) red[wave] = lmax;
        __syncthreads();
        if (tid == 0) {
            float bm = fmaxf(fmaxf(red[0], red[1]), fmaxf(red[2], red[3]));
            atomicMax(res + (MAX_ITER_N - 1), __float_as_uint(bm));
            __threadfence();
            atomicAdd(done, 1u);
            while (__hip_atomic_load(done, __ATOMIC_ACQUIRE, __HIP_MEMORY_SCOPE_AGENT) < 64u)
                __builtin_amdgcn_s_sleep(2);
        }
        __syncthreads();   // all 64 blocks' res[] contributions complete
    }

    // ---- merged decide: replay reference stopping rule ----
    int T;
    {
        float rv = 1e30f;
        if (tid < MAX_ITER_N)
            rv = __uint_as_float(__hip_atomic_load(res + tid, __ATOMIC_ACQUIRE, __HIP_MEMORY_SCOPE_AGENT));
        if (tid < 64) {
            unsigned long long m = __ballot((tid < MAX_ITER_N) && !(rv > F_TOL_F));
            if (tid == 0) red[0] = (float)(m ? (int)__ffsll(m) : MAX_ITER_N);
        }
        __syncthreads();
        T = (int)red[0];
    }
    if (bid == 0 && tid == 0)
        out[2 * BSZ * OUT_DIM] = (float)(T + 1);    // curr_iter
    if (T >= MAX_ITER_N) return;                    // hot path

    // ---- cold fp32 fallback for this block's 16 rows ----
    float (*zF)[257] = (float(*)[257])smem;
    {
        const int row = tid >> 4;
        const int c0 = (tid & 15) * 16;
        for (int i = 0; i < 16; ++i)
            zF[row][c0 + i] = outz[(r0 + row) * OUT_DIM + c0 + i];
        __syncthreads();
        const int j = tid;
        const float bj = bp[j];
        for (int t = 0; t < T; ++t) {
            float acc[16] = {};
            for (int k = 0; k < OUT_DIM; ++k) {
                float wv = WzProj[j * OUT_DIM + k];
#pragma unroll
                for (int r = 0; r < 16; ++r) acc[r] += zF[r][k] * wv;
            }
            __syncthreads();
#pragma unroll
            for (int r = 0; r < 16; ++r) {
                float v = acc[r] + bj;
                if (j >= FREE_NUM_N) v = fmaxf(v, 0.0f);
                zF[r][j] = v;
            }
            __syncthreads();
        }
        for (int i = 0; i < 16; ++i)
            out[(r0 + row) * OUT_DIM + c0 + i] = zF[row][c0 + i];
    }
}

extern "C" void kernel_launch(void* const* d_in, const int* in_sizes, int n_in,
                              void* d_out, int out_size, void* d_ws, size_t ws_size,
                              hipStream_t stream) {
    const float* b_primal = (const float*)d_in[0];
    const float* W0     = (const float*)d_in[1];
    const float* b0     = (const float*)d_in[2];
    const float* W1     = (const float*)d_in[3];
    const float* b1     = (const float*)d_in[4];
    const float* W2     = (const float*)d_in[5];
    const float* b2     = (const float*)d_in[6];
    const float* Amat   = (const float*)d_in[7];
    const float* b_vec  = (const float*)d_in[8];
    const float* WzProj = (const float*)d_in[9];
    const float* WbProj = (const float*)d_in[10];
    float* out = (float*)d_out;
    float* ws  = (float*)d_ws;

    // zero done/gcnt/res (48 uints) — in-stream, replay-safe
    hipMemsetAsync(ws, 0, 192, stream);

    hipLaunchKernelGGL(fused_k, dim3(256), dim3(256), 0, stream,
                       b_primal, W0, b0, W1, b1, W2, b2, Amat, b_vec,
                       WzProj, WbProj, out, ws);
}

// Round 3
// 166.567 us; speedup vs baseline: 1.9476x; 1.9476x over previous
//
#include <hip/hip_runtime.h>

typedef __attribute__((ext_vector_type(8))) __bf16 bf16x8;
typedef __attribute__((ext_vector_type(4))) float f32x4;

#define MAX_ITER_N 20
#define F_TOL_F 1e-6f
#define FREE_NUM_N 64

#define BSZ 1024
#define IN_DIM 512
#define HID 1024
#define OUT_DIM 256
#define M_CON 128

// workspace layout (float offsets); ctrl region [0..48) zeroed by g1 block 0
#define WS_DONE  0                         // uint: loop completion counter
#define WS_RES   8                         // 32 uints: per-iter residuals
#define WS_H1    304                       // h1 bf16 [1024][1024]
#define WS_H2    (WS_H1 + 524288)          // h2 bf16 [1024][1024]

__device__ __forceinline__ unsigned short f2bf(float f) {
    unsigned int u = __float_as_uint(f);
    u += 0x7fffu + ((u >> 16) & 1u);
    return (unsigned short)(u >> 16);
}

__device__ __forceinline__ unsigned int pk2(float a, float b) {
    return (unsigned int)f2bf(a) | ((unsigned int)f2bf(b) << 16);
}

__device__ __forceinline__ void gload_lds16(const unsigned short* g, unsigned short* l) {
    __builtin_amdgcn_global_load_lds(
        (const __attribute__((address_space(1))) unsigned int*)(const void*)g,
        (__attribute__((address_space(3))) unsigned int*)(void*)l, 16, 0, 0);
}

// fragment read from a 64x128 bf16 LDS tile with 4-bit XOR granule swizzle
__device__ __forceinline__ bf16x8 frag128(const unsigned short* lds, int row, int gc) {
    int phys = gc ^ (row & 15);
    return __builtin_bit_cast(bf16x8, *(const uint4*)(lds + row * 128 + phys * 8));
}

// ---- 64x64-tile MFMA GEMM kernel, BK=128, double-buffered LDS ----
// C[1024][1024] bf16 = act(A[1024][K] @ B[1024][K]^T + bias)
// AF32: A is f32 (inline convert, reg-staged). B always f32 reg-staged.
// A bf16 path: global_load_lds with pre-swizzled source.
template<int K, bool AF32, bool RELU>
__global__ __launch_bounds__(256) void gemm_k(
    const void* __restrict__ Ap, const float* __restrict__ Bf,
    const float* __restrict__ bias, unsigned short* __restrict__ C,
    float* __restrict__ ws)
{
    constexpr int NCH = K / 128;
    __shared__ __align__(16) unsigned short sA[2][8192];
    __shared__ __align__(16) unsigned short sB[2][8192];

    const int tid = threadIdx.x;
    if constexpr (AF32) {   // g1: zero ctrl region (replaces memset dispatch)
        if (blockIdx.x == 0 && tid < 48) ((unsigned int*)ws)[tid] = 0u;
    }
    const int w = tid >> 6;
    const int lane = tid & 63;
    const int ln = lane & 15;
    const int q  = lane >> 4;
    const int wr = w >> 1;
    const int wc = w & 1;
    const int row0 = (blockIdx.x >> 4) * 64;
    const int col0 = (blockIdx.x & 15) * 64;

    // reg-staging geometry: granule P = tid + 256*i; row=P>>4, gc=P&15
    int grow[4], ggc[4], lof[4];
#pragma unroll
    for (int i = 0; i < 4; ++i) {
        int P = tid + 256 * i;
        grow[i] = P >> 4; ggc[i] = P & 15;
        lof[i] = grow[i] * 128 + (ggc[i] ^ (grow[i] & 15)) * 8;
    }
    // A-bf16 gload_lds geometry (pre-swizzled source, lane-linear dest)
    int soff[4], dbase[4];
    const unsigned short* Ab_h = (const unsigned short*)Ap + row0 * K;
    const float*          Ab_f = (const float*)Ap + row0 * K;
    if constexpr (!AF32) {
#pragma unroll
        for (int i = 0; i < 4; ++i) {
            int P = w * 256 + i * 64 + lane;
            int row = P >> 4, pgc = P & 15;
            soff[i]  = row * K + (pgc ^ (row & 15)) * 8;
            dbase[i] = (w * 256 + i * 64) * 8;
        }
    }
    const float* Bb = Bf + col0 * K;

    float4 ra[8], rb[8];

    // ---- prologue: stage chunk 0 into buffer 0 ----
    if constexpr (AF32) {
#pragma unroll
        for (int i = 0; i < 4; ++i) {
            const float* s = Ab_f + grow[i] * K + ggc[i] * 8;
            ra[2*i]   = *(const float4*)s;
            ra[2*i+1] = *(const float4*)(s + 4);
        }
    } else {
#pragma unroll
        for (int i = 0; i < 4; ++i) gload_lds16(Ab_h + soff[i], &sA[0][dbase[i]]);
    }
#pragma unroll
    for (int i = 0; i < 4; ++i) {
        const float* s = Bb + grow[i] * K + ggc[i] * 8;
        rb[2*i]   = *(const float4*)s;
        rb[2*i+1] = *(const float4*)(s + 4);
    }
    if constexpr (AF32) {
#pragma unroll
        for (int i = 0; i < 4; ++i)
            *(uint4*)(&sA[0][lof[i]]) = (uint4){
                pk2(ra[2*i].x, ra[2*i].y),   pk2(ra[2*i].z, ra[2*i].w),
                pk2(ra[2*i+1].x, ra[2*i+1].y), pk2(ra[2*i+1].z, ra[2*i+1].w)};
    }
#pragma unroll
    for (int i = 0; i < 4; ++i)
        *(uint4*)(&sB[0][lof[i]]) = (uint4){
            pk2(rb[2*i].x, rb[2*i].y),   pk2(rb[2*i].z, rb[2*i].w),
            pk2(rb[2*i+1].x, rb[2*i+1].y), pk2(rb[2*i+1].z, rb[2*i+1].w)};

    f32x4 acc[2][2];
#pragma unroll
    for (int rm = 0; rm < 2; ++rm)
#pragma unroll
        for (int cn = 0; cn < 2; ++cn)
            acc[rm][cn] = (f32x4){0.f, 0.f, 0.f, 0.f};

    for (int c = 0; c < NCH; ++c) {
        __syncthreads();                     // buf[c&1] staging complete
        const int nb = (c + 1) & 1;
        if (c + 1 < NCH) {                   // issue next-chunk loads (hide under MFMA)
            const int koff = (c + 1) * 128;
            if constexpr (AF32) {
#pragma unroll
                for (int i = 0; i < 4; ++i) {
                    const float* s = Ab_f + grow[i] * K + koff + ggc[i] * 8;
                    ra[2*i]   = *(const float4*)s;
                    ra[2*i+1] = *(const float4*)(s + 4);
                }
            } else {
#pragma unroll
                for (int i = 0; i < 4; ++i)
                    gload_lds16(Ab_h + koff + soff[i], &sA[nb][dbase[i]]);
            }
#pragma unroll
            for (int i = 0; i < 4; ++i) {
                const float* s = Bb + grow[i] * K + koff + ggc[i] * 8;
                rb[2*i]   = *(const float4*)s;
                rb[2*i+1] = *(const float4*)(s + 4);
            }
        }
        const unsigned short* Ac = sA[c & 1];
        const unsigned short* Bc = sB[c & 1];
#pragma unroll
        for (int ks = 0; ks < 4; ++ks) {
            bf16x8 af0 = frag128(Ac, wr * 32 + ln,      ks * 4 + q);
            bf16x8 af1 = frag128(Ac, wr * 32 + 16 + ln, ks * 4 + q);
            bf16x8 bf0 = frag128(Bc, wc * 32 + ln,      ks * 4 + q);
            bf16x8 bf1 = frag128(Bc, wc * 32 + 16 + ln, ks * 4 + q);
            acc[0][0] = __builtin_amdgcn_mfma_f32_16x16x32_bf16(af0, bf0, acc[0][0], 0, 0, 0);
            acc[0][1] = __builtin_amdgcn_mfma_f32_16x16x32_bf16(af0, bf1, acc[0][1], 0, 0, 0);
            acc[1][0] = __builtin_amdgcn_mfma_f32_16x16x32_bf16(af1, bf0, acc[1][0], 0, 0, 0);
            acc[1][1] = __builtin_amdgcn_mfma_f32_16x16x32_bf16(af1, bf1, acc[1][1], 0, 0, 0);
        }
        if (c + 1 < NCH) {                   // cvt + write staged regs → buf nb
            if constexpr (AF32) {
#pragma unroll
                for (int i = 0; i < 4; ++i)
                    *(uint4*)(&sA[nb][lof[i]]) = (uint4){
                        pk2(ra[2*i].x, ra[2*i].y),   pk2(ra[2*i].z, ra[2*i].w),
                        pk2(ra[2*i+1].x, ra[2*i+1].y), pk2(ra[2*i+1].z, ra[2*i+1].w)};
            }
#pragma unroll
            for (int i = 0; i < 4; ++i)
                *(uint4*)(&sB[nb][lof[i]]) = (uint4){
                    pk2(rb[2*i].x, rb[2*i].y),   pk2(rb[2*i].z, rb[2*i].w),
                    pk2(rb[2*i+1].x, rb[2*i+1].y), pk2(rb[2*i+1].z, rb[2*i+1].w)};
        }
    }

#pragma unroll
    for (int cn = 0; cn < 2; ++cn) {
        const int cc = col0 + wc * 32 + cn * 16 + ln;
        const float bv = bias[cc];
#pragma unroll
        for (int rm = 0; rm < 2; ++rm)
#pragma unroll
            for (int i = 0; i < 4; ++i) {
                int r = row0 + wr * 32 + rm * 16 + q * 4 + i;
                float v = acc[rm][cn][i] + bv;
                if (RELU) v = fmaxf(v, 0.0f);
                C[r * HID + cc] = f2bf(v);
            }
    }
}

// ---- K3: self-contained per-block gemm3 slab + 20-iter loop + decide + fallback ----
// 64 blocks; block b owns rows [16b, 16b+16) end-to-end. No grid barrier needed
// before the loop because each block's z0 is exactly its own gemm3 output.
__global__ __launch_bounds__(256, 1) void k3_k(
    const float* __restrict__ W2, const float* __restrict__ b2v,
    const float* __restrict__ Am, const float* __restrict__ b_vec,
    const float* __restrict__ Wz, const float* __restrict__ WbP,
    float* __restrict__ out, float* __restrict__ ws)
{
    __shared__ __align__(16) unsigned short hS[16 * 1024];  // swizzled h2 slab (reused as zF)
    __shared__ __align__(16) unsigned short zS[16][264];
    __shared__ float bpS[256];
    __shared__ float red[8];

    unsigned int* done = (unsigned int*)ws;
    unsigned int* res  = (unsigned int*)(ws + WS_RES);
    const unsigned short* h2c = (const unsigned short*)(ws + WS_H2);
    float* outz = out + BSZ * OUT_DIM;

    const int tid  = threadIdx.x;
    const int wave = tid >> 6;
    const int lane = tid & 63;
    const int ln   = lane & 15;
    const int q    = lane >> 4;
    const int bid  = blockIdx.x;
    const int r0   = bid * 16;

    // stage h2[r0:r0+16][0:1024] -> hS (swizzled) via gload_lds, pre-swizzled source
#pragma unroll
    for (int i = 0; i < 8; ++i) {
        int G = wave * 512 + i * 64 + lane;          // granule index (lane-linear dest)
        int row = G >> 7, phys = G & 127;
        int gc = (phys & ~15) | ((phys & 15) ^ (row & 15));
        gload_lds16(h2c + (r0 + row) * HID + gc * 8, &hS[(wave * 512 + i * 64) * 8]);
    }
    // bias_proj: bp[j] = dot(b_vec, WbProj[j])
    {
        float s = 0.0f;
        for (int k = 0; k < M_CON; ++k) s += b_vec[k] * WbP[tid * M_CON + k];
        bpS[tid] = s;
    }
    __syncthreads();   // hS + bpS ready (vmcnt drained by barrier)

    int colg[4];
#pragma unroll
    for (int nt = 0; nt < 4; ++nt) colg[nt] = wave * 64 + nt * 16 + ln;

    // ---- gemm3: acc3 = h2_slab @ W2^T (W2 streamed f32 -> bf16) ----
    f32x4 acc3[4];
#pragma unroll
    for (int nt = 0; nt < 4; ++nt) acc3[nt] = (f32x4){0.f, 0.f, 0.f, 0.f};
#pragma unroll 2
    for (int ks = 0; ks < 32; ++ks) {
        int gci = ks * 4 + q;
        int phys = (gci & ~15) | ((gci & 15) ^ ln);
        bf16x8 af = __builtin_bit_cast(bf16x8, *(const uint4*)&hS[ln * 1024 + phys * 8]);
        float4 w0[4], w1[4];
#pragma unroll
        for (int nt = 0; nt < 4; ++nt) {
            const float* p = W2 + colg[nt] * HID + ks * 32 + q * 8;
            w0[nt] = *(const float4*)p;
            w1[nt] = *(const float4*)(p + 4);
        }
#pragma unroll
        for (int nt = 0; nt < 4; ++nt) {
            uint4 uv = {pk2(w0[nt].x, w0[nt].y), pk2(w0[nt].z, w0[nt].w),
                        pk2(w1[nt].x, w1[nt].y), pk2(w1[nt].z, w1[nt].w)};
            acc3[nt] = __builtin_amdgcn_mfma_f32_16x16x32_bf16(
                af, __builtin_bit_cast(bf16x8, uv), acc3[nt], 0, 0, 0);
        }
    }

    // epilogue: write out0 (f32) and seed zS = bf16(out0)
#pragma unroll
    for (int nt = 0; nt < 4; ++nt) {
        float bv = b2v[colg[nt]];
#pragma unroll
        for (int i = 0; i < 4; ++i) {
            float v = acc3[nt][i] + bv;
            outz[(r0 + q * 4 + i) * OUT_DIM + colg[nt]] = v;
            zS[q * 4 + i][colg[nt]] = f2bf(v);
        }
    }

    // register-resident A and Wz fragments (converted f32 -> bf16 inline)
    bf16x8 afr[2][8];
    float bvv[2];
#pragma unroll
    for (int mt = 0; mt < 2; ++mt) {
        int m = wave * 32 + mt * 16 + ln;
        bvv[mt] = b_vec[m];
#pragma unroll
        for (int ks = 0; ks < 8; ++ks) {
            const float* p = Am + m * OUT_DIM + ks * 32 + q * 8;
            float4 a0 = *(const float4*)p, a1 = *(const float4*)(p + 4);
            afr[mt][ks] = __builtin_bit_cast(bf16x8,
                (uint4){pk2(a0.x, a0.y), pk2(a0.z, a0.w), pk2(a1.x, a1.y), pk2(a1.z, a1.w)});
        }
    }
    float bpv[4];
    bf16x8 wzfr[4][8];
#pragma unroll
    for (int nt = 0; nt < 4; ++nt) {
        bpv[nt] = bpS[colg[nt]];
#pragma unroll
        for (int ks = 0; ks < 8; ++ks) {
            const float* p = Wz + colg[nt] * OUT_DIM + ks * 32 + q * 8;
            float4 a0 = *(const float4*)p, a1 = *(const float4*)(p + 4);
            wzfr[nt][ks] = __builtin_bit_cast(bf16x8,
                (uint4){pk2(a0.x, a0.y), pk2(a0.z, a0.w), pk2(a1.x, a1.y), pk2(a1.z, a1.w)});
        }
    }
    __syncthreads();   // zS seed complete

    bf16x8 zfr[8];
#pragma unroll
    for (int ks = 0; ks < 8; ++ks)
        zfr[ks] = __builtin_bit_cast(bf16x8, *(const uint4*)&zS[ln][ks * 32 + q * 8]);

    const f32x4 zero4 = {0.f, 0.f, 0.f, 0.f};

    for (int t = 1; t <= MAX_ITER_N; ++t) {
        f32x4 acc[4];
        f32x4 acc2[2];
#pragma unroll
        for (int nt = 0; nt < 4; ++nt) acc[nt] = zero4;
        acc2[0] = zero4; acc2[1] = zero4;
#pragma unroll
        for (int ks = 0; ks < 8; ++ks) {
#pragma unroll
            for (int nt = 0; nt < 4; ++nt)
                acc[nt] = __builtin_amdgcn_mfma_f32_16x16x32_bf16(zfr[ks], wzfr[nt][ks], acc[nt], 0, 0, 0);
            if (t > 1) {
#pragma unroll
                for (int mt = 0; mt < 2; ++mt)
                    acc2[mt] = __builtin_amdgcn_mfma_f32_16x16x32_bf16(zfr[ks], afr[mt][ks], acc2[mt], 0, 0, 0);
            }
        }
        float vals[4][4];
#pragma unroll
        for (int nt = 0; nt < 4; ++nt)
#pragma unroll
            for (int i = 0; i < 4; ++i) {
                float v = acc[nt][i] + bpv[nt];
                if (colg[nt] >= FREE_NUM_N) v = fmaxf(v, 0.0f);
                vals[nt][i] = v;
            }
        if (t > 1) {   // residual of z_{t-1} -> res[t-2]
            float lmax = 0.0f;
#pragma unroll
            for (int mt = 0; mt < 2; ++mt)
#pragma unroll
                for (int i = 0; i < 4; ++i)
                    lmax = fmaxf(lmax, fabsf(acc2[mt][i] - bvv[mt]));
#pragma unroll
            for (int off = 32; off > 0; off >>= 1)
                lmax = fmaxf(lmax, __shfl_xor(lmax, off));
            if (lane == 0) red[wave] = lmax;
        }
        if (t == MAX_ITER_N) {
#pragma unroll
            for (int nt = 0; nt < 4; ++nt)
#pragma unroll
                for (int i = 0; i < 4; ++i)
                    out[(r0 + q * 4 + i) * OUT_DIM + colg[nt]] = vals[nt][i];
        }
        __syncthreads();   // S1: reads of zS done + red written
        if (t > 1 && tid == 0) {
            float bm = fmaxf(fmaxf(red[0], red[1]), fmaxf(red[2], red[3]));
            atomicMax(res + (t - 2), __float_as_uint(bm));
        }
#pragma unroll
        for (int nt = 0; nt < 4; ++nt)
#pragma unroll
            for (int i = 0; i < 4; ++i)
                zS[q * 4 + i][colg[nt]] = f2bf(vals[nt][i]);
        __syncthreads();   // S2: zS = z_t complete
#pragma unroll
        for (int ks = 0; ks < 8; ++ks)
            zfr[ks] = __builtin_bit_cast(bf16x8, *(const uint4*)&zS[ln][ks * 32 + q * 8]);
    }

    {   // final residual of z_20 -> res[19], then 64-block completion
        f32x4 acc2[2];
        acc2[0] = zero4; acc2[1] = zero4;
#pragma unroll
        for (int ks = 0; ks < 8; ++ks)
#pragma unroll
            for (int mt = 0; mt < 2; ++mt)
                acc2[mt] = __builtin_amdgcn_mfma_f32_16x16x32_bf16(zfr[ks], afr[mt][ks], acc2[mt], 0, 0, 0);
        float lmax = 0.0f;
#pragma unroll
        for (int mt = 0; mt < 2; ++mt)
#pragma unroll
            for (int i = 0; i < 4; ++i)
                lmax = fmaxf(lmax, fabsf(acc2[mt][i] - bvv[mt]));
#pragma unroll
        for (int off = 32; off > 0; off >>= 1)
            lmax = fmaxf(lmax, __shfl_xor(lmax, off));
        if (lane == 0) red[wave] = lmax;
        __syncthreads();
        if (tid == 0) {
            float bm = fmaxf(fmaxf(red[0], red[1]), fmaxf(red[2], red[3]));
            atomicMax(res + (MAX_ITER_N - 1), __float_as_uint(bm));
            __threadfence();
            atomicAdd(done, 1u);
            while (__hip_atomic_load(done, __ATOMIC_ACQUIRE, __HIP_MEMORY_SCOPE_AGENT) < 64u)
                __builtin_amdgcn_s_sleep(2);
        }
        __syncthreads();   // all 64 blocks' res[] contributions complete
    }

    // ---- decide: replay reference stopping rule ----
    int T;
    {
        float rv = 1e30f;
        if (tid < MAX_ITER_N)
            rv = __uint_as_float(__hip_atomic_load(res + tid, __ATOMIC_ACQUIRE, __HIP_MEMORY_SCOPE_AGENT));
        if (tid < 64) {
            unsigned long long m = __ballot((tid < MAX_ITER_N) && !(rv > F_TOL_F));
            if (tid == 0) red[0] = (float)(m ? (int)__ffsll(m) : MAX_ITER_N);
        }
        __syncthreads();
        T = (int)red[0];
    }
    if (bid == 0 && tid == 0)
        out[2 * BSZ * OUT_DIM] = (float)(T + 1);    // curr_iter
    if (T >= MAX_ITER_N) return;                    // hot path

    // ---- cold fp32 fallback for this block's 16 rows (hS reused as zF) ----
    float (*zF)[257] = (float(*)[257])hS;
    {
        const int row = tid >> 4;
        const int c0 = (tid & 15) * 16;
        for (int i = 0; i < 16; ++i)
            zF[row][c0 + i] = outz[(r0 + row) * OUT_DIM + c0 + i];
        __syncthreads();
        const int j = tid;
        const float bj = bpS[j];
        for (int t = 0; t < T; ++t) {
            float acc[16] = {};
            for (int k = 0; k < OUT_DIM; ++k) {
                float wv = Wz[j * OUT_DIM + k];
#pragma unroll
                for (int r = 0; r < 16; ++r) acc[r] += zF[r][k] * wv;
            }
            __syncthreads();
#pragma unroll
            for (int r = 0; r < 16; ++r) {
                float v = acc[r] + bj;
                if (j >= FREE_NUM_N) v = fmaxf(v, 0.0f);
                zF[r][j] = v;
            }
            __syncthreads();
        }
        for (int i = 0; i < 16; ++i)
            out[(r0 + row) * OUT_DIM + c0 + i] = zF[row][c0 + i];
    }
}

extern "C" void kernel_launch(void* const* d_in, const int* in_sizes, int n_in,
                              void* d_out, int out_size, void* d_ws, size_t ws_size,
                              hipStream_t stream) {
    const float* b_primal = (const float*)d_in[0];
    const float* W0     = (const float*)d_in[1];
    const float* b0     = (const float*)d_in[2];
    const float* W1     = (const float*)d_in[3];
    const float* b1     = (const float*)d_in[4];
    const float* W2     = (const float*)d_in[5];
    const float* b2     = (const float*)d_in[6];
    const float* Amat   = (const float*)d_in[7];
    const float* b_vec  = (const float*)d_in[8];
    const float* WzProj = (const float*)d_in[9];
    const float* WbProj = (const float*)d_in[10];
    float* out = (float*)d_out;
    float* ws  = (float*)d_ws;

    unsigned short* h1c = (unsigned short*)(ws + WS_H1);
    unsigned short* h2c = (unsigned short*)(ws + WS_H2);

    // g1: h1 = relu(x @ W0^T + b0)   (A,B f32 inline-converted; zeroes ctrl)
    hipLaunchKernelGGL((gemm_k<IN_DIM, true, true>), dim3(256), dim3(256), 0, stream,
                       (const void*)b_primal, W0, b0, h1c, ws);
    // g2: h2 = relu(h1 @ W1^T + b1)  (A bf16 via gload_lds; B f32 inline)
    hipLaunchKernelGGL((gemm_k<HID, false, true>), dim3(256), dim3(256), 0, stream,
                       (const void*)h1c, W1, b1, h2c, ws);
    // k3: per-block gemm3 slab + 20-iter loop + decide + fallback
    hipLaunchKernelGGL(k3_k, dim3(64), dim3(256), 0, stream,
                       W2, b2, Amat, b_vec, WzProj, WbProj, out, ws);
}

// Round 4
// 157.648 us; speedup vs baseline: 2.0578x; 1.0566x over previous
//
#include <hip/hip_runtime.h>

typedef __attribute__((ext_vector_type(8))) __bf16 bf16x8;
typedef __attribute__((ext_vector_type(4))) float f32x4;

#define MAX_ITER_N 20
#define F_TOL_F 1e-6f
#define FREE_NUM_N 64

#define BSZ 1024
#define IN_DIM 512
#define HID 1024
#define OUT_DIM 256
#define M_CON 128

// workspace layout (float offsets); ctrl region [0..48) zeroed by g1 extra block
#define WS_DONE  0                         // uint: loop completion counter
#define WS_RES   8                         // 32 uints: per-iter residuals
#define WS_BP    48                        // 256 f32: bias_proj
#define WS_H1    304                       // h1 bf16 [1024][1024]
#define WS_H2    (WS_H1 + 524288)          // h2 bf16 [1024][1024]
#define WS_W2C   (WS_H2 + 524288)          // W2 bf16 [256][1024]
#define WS_WZG   (WS_W2C + 131072)         // Wz bf16 [256][256]
#define WS_AG    (WS_WZG + 32768)          // A  bf16 [128][256]

__device__ __forceinline__ unsigned short f2bf(float f) {
    unsigned int u = __float_as_uint(f);
    u += 0x7fffu + ((u >> 16) & 1u);
    return (unsigned short)(u >> 16);
}

__device__ __forceinline__ unsigned int pk2(float a, float b) {
    return (unsigned int)f2bf(a) | ((unsigned int)f2bf(b) << 16);
}

__device__ __forceinline__ void cvt16(const float* s, unsigned short* d) {
    float4 v0 = *(const float4*)s,       v1 = *(const float4*)(s + 4),
           v2 = *(const float4*)(s + 8), v3 = *(const float4*)(s + 12);
    *(uint4*)d       = (uint4){pk2(v0.x, v0.y), pk2(v0.z, v0.w), pk2(v1.x, v1.y), pk2(v1.z, v1.w)};
    *(uint4*)(d + 8) = (uint4){pk2(v2.x, v2.y), pk2(v2.z, v2.w), pk2(v3.x, v3.y), pk2(v3.z, v3.w)};
}

__device__ __forceinline__ void gload_lds16(const unsigned short* g, unsigned short* l) {
    __builtin_amdgcn_global_load_lds(
        (const __attribute__((address_space(1))) unsigned int*)(const void*)g,
        (__attribute__((address_space(3))) unsigned int*)(void*)l, 16, 0, 0);
}

// fragment read from a 64x128 bf16 LDS tile with 4-bit XOR granule swizzle
__device__ __forceinline__ bf16x8 frag128(const unsigned short* lds, int row, int gc) {
    int phys = gc ^ (row & 15);
    return __builtin_bit_cast(bf16x8, *(const uint4*)(lds + row * 128 + phys * 8));
}

// ---- 64x64-tile MFMA GEMM kernel, BK=128, double-buffered LDS ----
// C[1024][1024] bf16 = act(A[1024][K] @ B[1024][K]^T + bias)
// AF32 (g1): A is f32 (inline convert, reg-staged); extra blocks (>=256) do
// weight conversions + bias_proj + ctrl-zero in parallel with the GEMM.
template<int K, bool AF32, bool RELU>
__global__ __launch_bounds__(256) void gemm_k(
    const void* __restrict__ Ap, const float* __restrict__ Bf,
    const float* __restrict__ bias, unsigned short* __restrict__ C,
    float* __restrict__ ws,
    const float* __restrict__ W2, const float* __restrict__ Wz,
    const float* __restrict__ Am, const float* __restrict__ b_vec,
    const float* __restrict__ WbP)
{
    constexpr int NCH = K / 128;
    __shared__ __align__(16) unsigned short sA[2][8192];
    __shared__ __align__(16) unsigned short sB[2][8192];

    const int tid = threadIdx.x;

    if constexpr (AF32) {
        if (blockIdx.x >= 256) {            // side work, overlapped with GEMM
            int eb = blockIdx.x - 256;
            unsigned short* W2c = (unsigned short*)(ws + WS_W2C);
            unsigned short* WzG = (unsigned short*)(ws + WS_WZG);
            unsigned short* AG  = (unsigned short*)(ws + WS_AG);
            float* bp = ws + WS_BP;
            if (eb < 64) {                  // W2: 262144 floats -> bf16
                int base = eb * 4096 + tid * 16;
                cvt16(W2 + base, W2c + base);
            } else if (eb < 80) {           // Wz: 65536 floats
                int base = (eb - 64) * 4096 + tid * 16;
                cvt16(Wz + base, WzG + base);
            } else if (eb < 88) {           // Am: 32768 floats
                int base = (eb - 80) * 4096 + tid * 16;
                cvt16(Am + base, AG + base);
            } else {                        // 8 blocks: bias_proj, coalesced
                if (eb == 88 && tid < 48) ((unsigned int*)ws)[tid] = 0u;
                int j  = (eb - 88) * 32 + (tid >> 3);
                int kg = tid & 7;
                const float* p = WbP + j * M_CON + kg * 16;
                float s = 0.0f;
#pragma unroll
                for (int i = 0; i < 16; ++i) s += p[i] * b_vec[kg * 16 + i];
#pragma unroll
                for (int off = 4; off > 0; off >>= 1) s += __shfl_xor(s, off);
                if (kg == 0) bp[j] = s;
            }
            return;
        }
    }

    const int w = tid >> 6;
    const int lane = tid & 63;
    const int ln = lane & 15;
    const int q  = lane >> 4;
    const int wr = w >> 1;
    const int wc = w & 1;
    const int row0 = (blockIdx.x >> 4) * 64;
    const int col0 = (blockIdx.x & 15) * 64;

    // reg-staging geometry: granule P = tid + 256*i; row=P>>4, gc=P&15
    int grow[4], ggc[4], lof[4];
#pragma unroll
    for (int i = 0; i < 4; ++i) {
        int P = tid + 256 * i;
        grow[i] = P >> 4; ggc[i] = P & 15;
        lof[i] = grow[i] * 128 + (ggc[i] ^ (grow[i] & 15)) * 8;
    }
    // A-bf16 gload_lds geometry (pre-swizzled source, lane-linear dest)
    int soff[4], dbase[4];
    const unsigned short* Ab_h = (const unsigned short*)Ap + row0 * K;
    const float*          Ab_f = (const float*)Ap + row0 * K;
    if constexpr (!AF32) {
#pragma unroll
        for (int i = 0; i < 4; ++i) {
            int P = w * 256 + i * 64 + lane;
            int row = P >> 4, pgc = P & 15;
            soff[i]  = row * K + (pgc ^ (row & 15)) * 8;
            dbase[i] = (w * 256 + i * 64) * 8;
        }
    }
    const float* Bb = Bf + col0 * K;

    float4 ra[8], rb[8];

    // ---- prologue: stage chunk 0 into buffer 0 ----
    if constexpr (AF32) {
#pragma unroll
        for (int i = 0; i < 4; ++i) {
            const float* s = Ab_f + grow[i] * K + ggc[i] * 8;
            ra[2*i]   = *(const float4*)s;
            ra[2*i+1] = *(const float4*)(s + 4);
        }
    } else {
#pragma unroll
        for (int i = 0; i < 4; ++i) gload_lds16(Ab_h + soff[i], &sA[0][dbase[i]]);
    }
#pragma unroll
    for (int i = 0; i < 4; ++i) {
        const float* s = Bb + grow[i] * K + ggc[i] * 8;
        rb[2*i]   = *(const float4*)s;
        rb[2*i+1] = *(const float4*)(s + 4);
    }
    if constexpr (AF32) {
#pragma unroll
        for (int i = 0; i < 4; ++i)
            *(uint4*)(&sA[0][lof[i]]) = (uint4){
                pk2(ra[2*i].x, ra[2*i].y),   pk2(ra[2*i].z, ra[2*i].w),
                pk2(ra[2*i+1].x, ra[2*i+1].y), pk2(ra[2*i+1].z, ra[2*i+1].w)};
    }
#pragma unroll
    for (int i = 0; i < 4; ++i)
        *(uint4*)(&sB[0][lof[i]]) = (uint4){
            pk2(rb[2*i].x, rb[2*i].y),   pk2(rb[2*i].z, rb[2*i].w),
            pk2(rb[2*i+1].x, rb[2*i+1].y), pk2(rb[2*i+1].z, rb[2*i+1].w)};

    f32x4 acc[2][2];
#pragma unroll
    for (int rm = 0; rm < 2; ++rm)
#pragma unroll
        for (int cn = 0; cn < 2; ++cn)
            acc[rm][cn] = (f32x4){0.f, 0.f, 0.f, 0.f};

    for (int c = 0; c < NCH; ++c) {
        __syncthreads();                     // buf[c&1] staging complete
        const int nb = (c + 1) & 1;
        if (c + 1 < NCH) {                   // issue next-chunk loads (hide under MFMA)
            const int koff = (c + 1) * 128;
            if constexpr (AF32) {
#pragma unroll
                for (int i = 0; i < 4; ++i) {
                    const float* s = Ab_f + grow[i] * K + koff + ggc[i] * 8;
                    ra[2*i]   = *(const float4*)s;
                    ra[2*i+1] = *(const float4*)(s + 4);
                }
            } else {
#pragma unroll
                for (int i = 0; i < 4; ++i)
                    gload_lds16(Ab_h + koff + soff[i], &sA[nb][dbase[i]]);
            }
#pragma unroll
            for (int i = 0; i < 4; ++i) {
                const float* s = Bb + grow[i] * K + koff + ggc[i] * 8;
                rb[2*i]   = *(const float4*)s;
                rb[2*i+1] = *(const float4*)(s + 4);
            }
        }
        const unsigned short* Ac = sA[c & 1];
        const unsigned short* Bc = sB[c & 1];
#pragma unroll
        for (int ks = 0; ks < 4; ++ks) {
            bf16x8 af0 = frag128(Ac, wr * 32 + ln,      ks * 4 + q);
            bf16x8 af1 = frag128(Ac, wr * 32 + 16 + ln, ks * 4 + q);
            bf16x8 bf0 = frag128(Bc, wc * 32 + ln,      ks * 4 + q);
            bf16x8 bf1 = frag128(Bc, wc * 32 + 16 + ln, ks * 4 + q);
            acc[0][0] = __builtin_amdgcn_mfma_f32_16x16x32_bf16(af0, bf0, acc[0][0], 0, 0, 0);
            acc[0][1] = __builtin_amdgcn_mfma_f32_16x16x32_bf16(af0, bf1, acc[0][1], 0, 0, 0);
            acc[1][0] = __builtin_amdgcn_mfma_f32_16x16x32_bf16(af1, bf0, acc[1][0], 0, 0, 0);
            acc[1][1] = __builtin_amdgcn_mfma_f32_16x16x32_bf16(af1, bf1, acc[1][1], 0, 0, 0);
        }
        if (c + 1 < NCH) {                   // cvt + write staged regs → buf nb
            if constexpr (AF32) {
#pragma unroll
                for (int i = 0; i < 4; ++i)
                    *(uint4*)(&sA[nb][lof[i]]) = (uint4){
                        pk2(ra[2*i].x, ra[2*i].y),   pk2(ra[2*i].z, ra[2*i].w),
                        pk2(ra[2*i+1].x, ra[2*i+1].y), pk2(ra[2*i+1].z, ra[2*i+1].w)};
            }
#pragma unroll
            for (int i = 0; i < 4; ++i)
                *(uint4*)(&sB[nb][lof[i]]) = (uint4){
                    pk2(rb[2*i].x, rb[2*i].y),   pk2(rb[2*i].z, rb[2*i].w),
                    pk2(rb[2*i+1].x, rb[2*i+1].y), pk2(rb[2*i+1].z, rb[2*i+1].w)};
        }
    }

#pragma unroll
    for (int cn = 0; cn < 2; ++cn) {
        const int cc = col0 + wc * 32 + cn * 16 + ln;
        const float bv = bias[cc];
#pragma unroll
        for (int rm = 0; rm < 2; ++rm)
#pragma unroll
            for (int i = 0; i < 4; ++i) {
                int r = row0 + wr * 32 + rm * 16 + q * 4 + i;
                float v = acc[rm][cn][i] + bv;
                if (RELU) v = fmaxf(v, 0.0f);
                C[r * HID + cc] = f2bf(v);
            }
    }
}

// ---- K3: per-block gemm3 slab + 20-iter loop + decide + fallback; 64 blocks ----
// All weights pre-converted to bf16 by g1's extra blocks: zero cvt VALU here.
__global__ __launch_bounds__(256, 1) void k3_k(
    const float* __restrict__ b2v, const float* __restrict__ b_vec,
    const float* __restrict__ Wzf, float* __restrict__ out,
    float* __restrict__ ws)
{
    __shared__ __align__(16) unsigned short hS[16 * 1024];  // swizzled h2 slab (reused as zF)
    __shared__ __align__(16) unsigned short zS[16][264];
    __shared__ float red[8];

    unsigned int* done = (unsigned int*)ws;
    unsigned int* res  = (unsigned int*)(ws + WS_RES);
    const float* bp = ws + WS_BP;
    const unsigned short* h2c = (const unsigned short*)(ws + WS_H2);
    const unsigned short* W2c = (const unsigned short*)(ws + WS_W2C);
    const unsigned short* WzG = (const unsigned short*)(ws + WS_WZG);
    const unsigned short* AG  = (const unsigned short*)(ws + WS_AG);
    float* outz = out + BSZ * OUT_DIM;

    const int tid  = threadIdx.x;
    const int wave = tid >> 6;
    const int lane = tid & 63;
    const int ln   = lane & 15;
    const int q    = lane >> 4;
    const int bid  = blockIdx.x;
    const int r0   = bid * 16;

    // stage h2[r0:r0+16][0:1024] -> hS (swizzled) via gload_lds, pre-swizzled source
#pragma unroll
    for (int i = 0; i < 8; ++i) {
        int G = wave * 512 + i * 64 + lane;          // granule index (lane-linear dest)
        int row = G >> 7, phys = G & 127;
        int gc = (phys & ~15) | ((phys & 15) ^ (row & 15));
        gload_lds16(h2c + (r0 + row) * HID + gc * 8, &hS[(wave * 512 + i * 64) * 8]);
    }

    int colg[4];
#pragma unroll
    for (int nt = 0; nt < 4; ++nt) colg[nt] = wave * 64 + nt * 16 + ln;

    // register-resident fragments: plain bf16 loads, issued early for MLP
    bf16x8 afr[2][8];
    float bvv[2];
#pragma unroll
    for (int mt = 0; mt < 2; ++mt) {
        int m = wave * 32 + mt * 16 + ln;
        bvv[mt] = b_vec[m];
#pragma unroll
        for (int ks = 0; ks < 8; ++ks)
            afr[mt][ks] = __builtin_bit_cast(bf16x8, *(const uint4*)(AG + m * OUT_DIM + ks * 32 + q * 8));
    }
    float bpv[4];
    bf16x8 wzfr[4][8];
#pragma unroll
    for (int nt = 0; nt < 4; ++nt) {
        bpv[nt] = bp[colg[nt]];
#pragma unroll
        for (int ks = 0; ks < 8; ++ks)
            wzfr[nt][ks] = __builtin_bit_cast(bf16x8, *(const uint4*)(WzG + colg[nt] * OUT_DIM + ks * 32 + q * 8));
    }
    __syncthreads();   // hS ready (barrier drains vmcnt)

    // ---- gemm3: acc3 = h2_slab @ W2c^T (bf16 direct) ----
    f32x4 acc3[4];
#pragma unroll
    for (int nt = 0; nt < 4; ++nt) acc3[nt] = (f32x4){0.f, 0.f, 0.f, 0.f};
#pragma unroll 4
    for (int ks = 0; ks < 32; ++ks) {
        int gci = ks * 4 + q;
        int phys = (gci & ~15) | ((gci & 15) ^ ln);
        bf16x8 af = __builtin_bit_cast(bf16x8, *(const uint4*)&hS[ln * 1024 + phys * 8]);
#pragma unroll
        for (int nt = 0; nt < 4; ++nt) {
            bf16x8 wf = __builtin_bit_cast(bf16x8, *(const uint4*)(W2c + colg[nt] * HID + ks * 32 + q * 8));
            acc3[nt] = __builtin_amdgcn_mfma_f32_16x16x32_bf16(af, wf, acc3[nt], 0, 0, 0);
        }
    }

    // epilogue: write out0 (f32) and seed zS = bf16(out0)
#pragma unroll
    for (int nt = 0; nt < 4; ++nt) {
        float bv = b2v[colg[nt]];
#pragma unroll
        for (int i = 0; i < 4; ++i) {
            float v = acc3[nt][i] + bv;
            outz[(r0 + q * 4 + i) * OUT_DIM + colg[nt]] = v;
            zS[q * 4 + i][colg[nt]] = f2bf(v);
        }
    }
    __syncthreads();   // zS seed complete

    bf16x8 zfr[8];
#pragma unroll
    for (int ks = 0; ks < 8; ++ks)
        zfr[ks] = __builtin_bit_cast(bf16x8, *(const uint4*)&zS[ln][ks * 32 + q * 8]);

    const f32x4 zero4 = {0.f, 0.f, 0.f, 0.f};

    for (int t = 1; t <= MAX_ITER_N; ++t) {
        f32x4 acc[4];
        f32x4 acc2[2];
#pragma unroll
        for (int nt = 0; nt < 4; ++nt) acc[nt] = zero4;
        acc2[0] = zero4; acc2[1] = zero4;
#pragma unroll
        for (int ks = 0; ks < 8; ++ks) {
#pragma unroll
            for (int nt = 0; nt < 4; ++nt)
                acc[nt] = __builtin_amdgcn_mfma_f32_16x16x32_bf16(zfr[ks], wzfr[nt][ks], acc[nt], 0, 0, 0);
            if (t > 1) {
#pragma unroll
                for (int mt = 0; mt < 2; ++mt)
                    acc2[mt] = __builtin_amdgcn_mfma_f32_16x16x32_bf16(zfr[ks], afr[mt][ks], acc2[mt], 0, 0, 0);
            }
        }
        float vals[4][4];
#pragma unroll
        for (int nt = 0; nt < 4; ++nt)
#pragma unroll
            for (int i = 0; i < 4; ++i) {
                float v = acc[nt][i] + bpv[nt];
                if (colg[nt] >= FREE_NUM_N) v = fmaxf(v, 0.0f);
                vals[nt][i] = v;
            }
        if (t > 1) {   // residual of z_{t-1} -> res[t-2]
            float lmax = 0.0f;
#pragma unroll
            for (int mt = 0; mt < 2; ++mt)
#pragma unroll
                for (int i = 0; i < 4; ++i)
                    lmax = fmaxf(lmax, fabsf(acc2[mt][i] - bvv[mt]));
#pragma unroll
            for (int off = 32; off > 0; off >>= 1)
                lmax = fmaxf(lmax, __shfl_xor(lmax, off));
            if (lane == 0) red[wave] = lmax;
        }
        if (t == MAX_ITER_N) {
#pragma unroll
            for (int nt = 0; nt < 4; ++nt)
#pragma unroll
                for (int i = 0; i < 4; ++i)
                    out[(r0 + q * 4 + i) * OUT_DIM + colg[nt]] = vals[nt][i];
        }
        __syncthreads();   // S1: reads of zS done + red written
        if (t > 1 && tid == 0) {
            float bm = fmaxf(fmaxf(red[0], red[1]), fmaxf(red[2], red[3]));
            atomicMax(res + (t - 2), __float_as_uint(bm));
        }
#pragma unroll
        for (int nt = 0; nt < 4; ++nt)
#pragma unroll
            for (int i = 0; i < 4; ++i)
                zS[q * 4 + i][colg[nt]] = f2bf(vals[nt][i]);
        __syncthreads();   // S2: zS = z_t complete
#pragma unroll
        for (int ks = 0; ks < 8; ++ks)
            zfr[ks] = __builtin_bit_cast(bf16x8, *(const uint4*)&zS[ln][ks * 32 + q * 8]);
    }

    {   // final residual of z_20 -> res[19], then 64-block completion
        f32x4 acc2[2];
        acc2[0] = zero4; acc2[1] = zero4;
#pragma unroll
        for (int ks = 0; ks < 8; ++ks)
#pragma unroll
            for (int mt = 0; mt < 2; ++mt)
                acc2[mt] = __builtin_amdgcn_mfma_f32_16x16x32_bf16(zfr[ks], afr[mt][ks], acc2[mt], 0, 0, 0);
        float lmax = 0.0f;
#pragma unroll
        for (int mt = 0; mt < 2; ++mt)
#pragma unroll
            for (int i = 0; i < 4; ++i)
                lmax = fmaxf(lmax, fabsf(acc2[mt][i] - bvv[mt]));
#pragma unroll
        for (int off = 32; off > 0; off >>= 1)
            lmax = fmaxf(lmax, __shfl_xor(lmax, off));
        if (lane == 0) red[wave] = lmax;
        __syncthreads();
        if (tid == 0) {
            float bm = fmaxf(fmaxf(red[0], red[1]), fmaxf(red[2], red[3]));
            atomicMax(res + (MAX_ITER_N - 1), __float_as_uint(bm));
            __threadfence();
            atomicAdd(done, 1u);
            while (__hip_atomic_load(done, __ATOMIC_ACQUIRE, __HIP_MEMORY_SCOPE_AGENT) < 64u)
                __builtin_amdgcn_s_sleep(2);
        }
        __syncthreads();   // all 64 blocks' res[] contributions complete
    }

    // ---- decide: replay reference stopping rule ----
    int T;
    {
        float rv = 1e30f;
        if (tid < MAX_ITER_N)
            rv = __uint_as_float(__hip_atomic_load(res + tid, __ATOMIC_ACQUIRE, __HIP_MEMORY_SCOPE_AGENT));
        if (tid < 64) {
            unsigned long long m = __ballot((tid < MAX_ITER_N) && !(rv > F_TOL_F));
            if (tid == 0) red[0] = (float)(m ? (int)__ffsll(m) : MAX_ITER_N);
        }
        __syncthreads();
        T = (int)red[0];
    }
    if (bid == 0 && tid == 0)
        out[2 * BSZ * OUT_DIM] = (float)(T + 1);    // curr_iter
    if (T >= MAX_ITER_N) return;                    // hot path

    // ---- cold fp32 fallback for this block's 16 rows (hS reused as zF) ----
    float (*zF)[257] = (float(*)[257])hS;
    {
        const int row = tid >> 4;
        const int c0 = (tid & 15) * 16;
        for (int i = 0; i < 16; ++i)
            zF[row][c0 + i] = outz[(r0 + row) * OUT_DIM + c0 + i];
        __syncthreads();
        const int j = tid;
        const float bj = bp[j];
        for (int t = 0; t < T; ++t) {
            float acc[16] = {};
            for (int k = 0; k < OUT_DIM; ++k) {
                float wv = Wzf[j * OUT_DIM + k];
#pragma unroll
                for (int r = 0; r < 16; ++r) acc[r] += zF[r][k] * wv;
            }
            __syncthreads();
#pragma unroll
            for (int r = 0; r < 16; ++r) {
                float v = acc[r] + bj;
                if (j >= FREE_NUM_N) v = fmaxf(v, 0.0f);
                zF[r][j] = v;
            }
            __syncthreads();
        }
        for (int i = 0; i < 16; ++i)
            out[(r0 + row) * OUT_DIM + c0 + i] = zF[row][c0 + i];
    }
}

extern "C" void kernel_launch(void* const* d_in, const int* in_sizes, int n_in,
                              void* d_out, int out_size, void* d_ws, size_t ws_size,
                              hipStream_t stream) {
    const float* b_primal = (const float*)d_in[0];
    const float* W0     = (const float*)d_in[1];
    const float* b0     = (const float*)d_in[2];
    const float* W1     = (const float*)d_in[3];
    const float* b1     = (const float*)d_in[4];
    const float* W2     = (const float*)d_in[5];
    const float* b2     = (const float*)d_in[6];
    const float* Amat   = (const float*)d_in[7];
    const float* b_vec  = (const float*)d_in[8];
    const float* WzProj = (const float*)d_in[9];
    const float* WbProj = (const float*)d_in[10];
    float* out = (float*)d_out;
    float* ws  = (float*)d_ws;

    unsigned short* h1c = (unsigned short*)(ws + WS_H1);
    unsigned short* h2c = (unsigned short*)(ws + WS_H2);

    // g1: h1 = relu(x @ W0^T + b0); extra 96 blocks convert W2/Wz/Am + bias_proj + ctrl-zero
    hipLaunchKernelGGL((gemm_k<IN_DIM, true, true>), dim3(352), dim3(256), 0, stream,
                       (const void*)b_primal, W0, b0, h1c, ws,
                       W2, WzProj, Amat, b_vec, WbProj);
    // g2: h2 = relu(h1 @ W1^T + b1)
    hipLaunchKernelGGL((gemm_k<HID, false, true>), dim3(256), dim3(256), 0, stream,
                       (const void*)h1c, W1, b1, h2c, ws,
                       nullptr, nullptr, nullptr, nullptr, nullptr);
    // k3: per-block gemm3 slab + 20-iter loop + decide + fallback
    hipLaunchKernelGGL(k3_k, dim3(64), dim3(256), 0, stream,
                       b2, b_vec, WzProj, out, ws);
}

// Round 5
// 142.051 us; speedup vs baseline: 2.2837x; 1.1098x over previous
//
#include <hip/hip_runtime.h>

typedef __attribute__((ext_vector_type(8))) __bf16 bf16x8;
typedef __attribute__((ext_vector_type(4))) float f32x4;

#define MAX_ITER_N 20
#define F_TOL_F 1e-6f
#define FREE_NUM_N 64

#define BSZ 1024
#define IN_DIM 512
#define HID 1024
#define OUT_DIM 256
#define M_CON 128

// workspace layout (float offsets); ctrl region [0..48) zeroed by g1 extra block
#define WS_DONE  0                         // uint: loop completion counter
#define WS_RES   8                         // 32 uints: per-iter residuals
#define WS_BP    48                        // 256 f32: bias_proj
#define WS_H1    304                       // h1 bf16 [1024][1024]
#define WS_H2    (WS_H1 + 524288)          // h2 bf16 [1024][1024]
#define WS_W2C   (WS_H2 + 524288)          // W2 bf16 [256][1024]
#define WS_WZG   (WS_W2C + 131072)         // Wz bf16 [256][256]
#define WS_AG    (WS_WZG + 32768)          // A  bf16 [128][256]

__device__ __forceinline__ unsigned short f2bf(float f) {
    unsigned int u = __float_as_uint(f);
    u += 0x7fffu + ((u >> 16) & 1u);
    return (unsigned short)(u >> 16);
}

__device__ __forceinline__ unsigned int pk2(float a, float b) {
    return (unsigned int)f2bf(a) | ((unsigned int)f2bf(b) << 16);
}

__device__ __forceinline__ void cvt16(const float* s, unsigned short* d) {
    float4 v0 = *(const float4*)s,       v1 = *(const float4*)(s + 4),
           v2 = *(const float4*)(s + 8), v3 = *(const float4*)(s + 12);
    *(uint4*)d       = (uint4){pk2(v0.x, v0.y), pk2(v0.z, v0.w), pk2(v1.x, v1.y), pk2(v1.z, v1.w)};
    *(uint4*)(d + 8) = (uint4){pk2(v2.x, v2.y), pk2(v2.z, v2.w), pk2(v3.x, v3.y), pk2(v3.z, v3.w)};
}

__device__ __forceinline__ void gload_lds16(const unsigned short* g, unsigned short* l) {
    __builtin_amdgcn_global_load_lds(
        (const __attribute__((address_space(1))) unsigned int*)(const void*)g,
        (__attribute__((address_space(3))) unsigned int*)(void*)l, 16, 0, 0);
}

// fragment read from a 64x128 bf16 LDS tile with 4-bit XOR granule swizzle
__device__ __forceinline__ bf16x8 frag128(const unsigned short* lds, int row, int gc) {
    int phys = gc ^ (row & 15);
    return __builtin_bit_cast(bf16x8, *(const uint4*)(lds + row * 128 + phys * 8));
}

// ---- 64x64-tile MFMA GEMM kernel, BK=128, double-buffered LDS ----
// C[1024][1024] bf16 = act(A[1024][K] @ B[1024][K]^T + bias)
// AF32 (g1): A is f32 (inline convert, reg-staged); extra blocks (>=256) do
// weight conversions + bias_proj + ctrl-zero in parallel with the GEMM.
template<int K, bool AF32, bool RELU>
__global__ __launch_bounds__(256) void gemm_k(
    const void* __restrict__ Ap, const float* __restrict__ Bf,
    const float* __restrict__ bias, unsigned short* __restrict__ C,
    float* __restrict__ ws,
    const float* __restrict__ W2, const float* __restrict__ Wz,
    const float* __restrict__ Am, const float* __restrict__ b_vec,
    const float* __restrict__ WbP)
{
    constexpr int NCH = K / 128;
    __shared__ __align__(16) unsigned short sA[2][8192];
    __shared__ __align__(16) unsigned short sB[2][8192];

    const int tid = threadIdx.x;

    if constexpr (AF32) {
        if (blockIdx.x >= 256) {            // side work, overlapped with GEMM
            int eb = blockIdx.x - 256;
            unsigned short* W2c = (unsigned short*)(ws + WS_W2C);
            unsigned short* WzG = (unsigned short*)(ws + WS_WZG);
            unsigned short* AG  = (unsigned short*)(ws + WS_AG);
            float* bp = ws + WS_BP;
            if (eb < 64) {                  // W2: 262144 floats -> bf16
                int base = eb * 4096 + tid * 16;
                cvt16(W2 + base, W2c + base);
            } else if (eb < 80) {           // Wz: 65536 floats
                int base = (eb - 64) * 4096 + tid * 16;
                cvt16(Wz + base, WzG + base);
            } else if (eb < 88) {           // Am: 32768 floats
                int base = (eb - 80) * 4096 + tid * 16;
                cvt16(Am + base, AG + base);
            } else {                        // 8 blocks: bias_proj, coalesced
                if (eb == 88 && tid < 48) ((unsigned int*)ws)[tid] = 0u;
                int j  = (eb - 88) * 32 + (tid >> 3);
                int kg = tid & 7;
                const float* p = WbP + j * M_CON + kg * 16;
                float s = 0.0f;
#pragma unroll
                for (int i = 0; i < 16; ++i) s += p[i] * b_vec[kg * 16 + i];
#pragma unroll
                for (int off = 4; off > 0; off >>= 1) s += __shfl_xor(s, off);
                if (kg == 0) bp[j] = s;
            }
            return;
        }
    }

    const int w = tid >> 6;
    const int lane = tid & 63;
    const int ln = lane & 15;
    const int q  = lane >> 4;
    const int wr = w >> 1;
    const int wc = w & 1;
    const int row0 = (blockIdx.x >> 4) * 64;
    const int col0 = (blockIdx.x & 15) * 64;

    // reg-staging geometry: granule P = tid + 256*i; row=P>>4, gc=P&15
    int grow[4], ggc[4], lof[4];
#pragma unroll
    for (int i = 0; i < 4; ++i) {
        int P = tid + 256 * i;
        grow[i] = P >> 4; ggc[i] = P & 15;
        lof[i] = grow[i] * 128 + (ggc[i] ^ (grow[i] & 15)) * 8;
    }
    // A-bf16 gload_lds geometry (pre-swizzled source, lane-linear dest)
    int soff[4], dbase[4];
    const unsigned short* Ab_h = (const unsigned short*)Ap + row0 * K;
    const float*          Ab_f = (const float*)Ap + row0 * K;
    if constexpr (!AF32) {
#pragma unroll
        for (int i = 0; i < 4; ++i) {
            int P = w * 256 + i * 64 + lane;
            int row = P >> 4, pgc = P & 15;
            soff[i]  = row * K + (pgc ^ (row & 15)) * 8;
            dbase[i] = (w * 256 + i * 64) * 8;
        }
    }
    const float* Bb = Bf + col0 * K;

    float4 ra[8], rb[8];

    // ---- prologue: stage chunk 0 into buffer 0 ----
    if constexpr (AF32) {
#pragma unroll
        for (int i = 0; i < 4; ++i) {
            const float* s = Ab_f + grow[i] * K + ggc[i] * 8;
            ra[2*i]   = *(const float4*)s;
            ra[2*i+1] = *(const float4*)(s + 4);
        }
    } else {
#pragma unroll
        for (int i = 0; i < 4; ++i) gload_lds16(Ab_h + soff[i], &sA[0][dbase[i]]);
    }
#pragma unroll
    for (int i = 0; i < 4; ++i) {
        const float* s = Bb + grow[i] * K + ggc[i] * 8;
        rb[2*i]   = *(const float4*)s;
        rb[2*i+1] = *(const float4*)(s + 4);
    }
    if constexpr (AF32) {
#pragma unroll
        for (int i = 0; i < 4; ++i)
            *(uint4*)(&sA[0][lof[i]]) = (uint4){
                pk2(ra[2*i].x, ra[2*i].y),   pk2(ra[2*i].z, ra[2*i].w),
                pk2(ra[2*i+1].x, ra[2*i+1].y), pk2(ra[2*i+1].z, ra[2*i+1].w)};
    }
#pragma unroll
    for (int i = 0; i < 4; ++i)
        *(uint4*)(&sB[0][lof[i]]) = (uint4){
            pk2(rb[2*i].x, rb[2*i].y),   pk2(rb[2*i].z, rb[2*i].w),
            pk2(rb[2*i+1].x, rb[2*i+1].y), pk2(rb[2*i+1].z, rb[2*i+1].w)};

    f32x4 acc[2][2];
#pragma unroll
    for (int rm = 0; rm < 2; ++rm)
#pragma unroll
        for (int cn = 0; cn < 2; ++cn)
            acc[rm][cn] = (f32x4){0.f, 0.f, 0.f, 0.f};

    for (int c = 0; c < NCH; ++c) {
        __syncthreads();                     // buf[c&1] staging complete
        const int nb = (c + 1) & 1;
        if (c + 1 < NCH) {                   // issue next-chunk loads (hide under MFMA)
            const int koff = (c + 1) * 128;
            if constexpr (AF32) {
#pragma unroll
                for (int i = 0; i < 4; ++i) {
                    const float* s = Ab_f + grow[i] * K + koff + ggc[i] * 8;
                    ra[2*i]   = *(const float4*)s;
                    ra[2*i+1] = *(const float4*)(s + 4);
                }
            } else {
#pragma unroll
                for (int i = 0; i < 4; ++i)
                    gload_lds16(Ab_h + koff + soff[i], &sA[nb][dbase[i]]);
            }
#pragma unroll
            for (int i = 0; i < 4; ++i) {
                const float* s = Bb + grow[i] * K + koff + ggc[i] * 8;
                rb[2*i]   = *(const float4*)s;
                rb[2*i+1] = *(const float4*)(s + 4);
            }
        }
        const unsigned short* Ac = sA[c & 1];
        const unsigned short* Bc = sB[c & 1];
#pragma unroll
        for (int ks = 0; ks < 4; ++ks) {
            bf16x8 af0 = frag128(Ac, wr * 32 + ln,      ks * 4 + q);
            bf16x8 af1 = frag128(Ac, wr * 32 + 16 + ln, ks * 4 + q);
            bf16x8 bf0 = frag128(Bc, wc * 32 + ln,      ks * 4 + q);
            bf16x8 bf1 = frag128(Bc, wc * 32 + 16 + ln, ks * 4 + q);
            acc[0][0] = __builtin_amdgcn_mfma_f32_16x16x32_bf16(af0, bf0, acc[0][0], 0, 0, 0);
            acc[0][1] = __builtin_amdgcn_mfma_f32_16x16x32_bf16(af0, bf1, acc[0][1], 0, 0, 0);
            acc[1][0] = __builtin_amdgcn_mfma_f32_16x16x32_bf16(af1, bf0, acc[1][0], 0, 0, 0);
            acc[1][1] = __builtin_amdgcn_mfma_f32_16x16x32_bf16(af1, bf1, acc[1][1], 0, 0, 0);
        }
        if (c + 1 < NCH) {                   // cvt + write staged regs → buf nb
            if constexpr (AF32) {
#pragma unroll
                for (int i = 0; i < 4; ++i)
                    *(uint4*)(&sA[nb][lof[i]]) = (uint4){
                        pk2(ra[2*i].x, ra[2*i].y),   pk2(ra[2*i].z, ra[2*i].w),
                        pk2(ra[2*i+1].x, ra[2*i+1].y), pk2(ra[2*i+1].z, ra[2*i+1].w)};
            }
#pragma unroll
            for (int i = 0; i < 4; ++i)
                *(uint4*)(&sB[nb][lof[i]]) = (uint4){
                    pk2(rb[2*i].x, rb[2*i].y),   pk2(rb[2*i].z, rb[2*i].w),
                    pk2(rb[2*i+1].x, rb[2*i+1].y), pk2(rb[2*i+1].z, rb[2*i+1].w)};
        }
    }

#pragma unroll
    for (int cn = 0; cn < 2; ++cn) {
        const int cc = col0 + wc * 32 + cn * 16 + ln;
        const float bv = bias[cc];
#pragma unroll
        for (int rm = 0; rm < 2; ++rm)
#pragma unroll
            for (int i = 0; i < 4; ++i) {
                int r = row0 + wr * 32 + rm * 16 + q * 4 + i;
                float v = acc[rm][cn][i] + bv;
                if (RELU) v = fmaxf(v, 0.0f);
                C[r * HID + cc] = f2bf(v);
            }
    }
}

// ---- K3: per-block gemm3 slab + 20-iter loop + decide + fallback ----
// 64 blocks x 512 threads (8 waves, 2/SIMD). Loop body touches NO global
// memory; per-iter residual maxima buffered in LDS, flushed once at the end
// as 20 parallel atomicMax ops.
__global__ __launch_bounds__(512, 1) void k3_k(
    const float* __restrict__ b2v, const float* __restrict__ b_vec,
    const float* __restrict__ Wzf, float* __restrict__ out,
    float* __restrict__ ws)
{
    __shared__ __align__(16) unsigned short hS[16 * 1024];  // swizzled h2 slab (reused as zF)
    __shared__ __align__(16) unsigned short zS[16][264];
    __shared__ float redL[MAX_ITER_N * 8];                  // [ri][wave]
    __shared__ float Tsh;

    unsigned int* done = (unsigned int*)ws;
    unsigned int* res  = (unsigned int*)(ws + WS_RES);
    const float* bp = ws + WS_BP;
    const unsigned short* h2c = (const unsigned short*)(ws + WS_H2);
    const unsigned short* W2c = (const unsigned short*)(ws + WS_W2C);
    const unsigned short* WzG = (const unsigned short*)(ws + WS_WZG);
    const unsigned short* AG  = (const unsigned short*)(ws + WS_AG);
    float* outz = out + BSZ * OUT_DIM;

    const int tid  = threadIdx.x;
    const int wave = tid >> 6;
    const int lane = tid & 63;
    const int ln   = lane & 15;
    const int q    = lane >> 4;
    const int bid  = blockIdx.x;
    const int r0   = bid * 16;

    // stage h2[r0:r0+16][0:1024] -> hS (swizzled): 2048 granules / 8 waves
#pragma unroll
    for (int i = 0; i < 4; ++i) {
        int G = wave * 256 + i * 64 + lane;          // granule (lane-linear dest)
        int row = G >> 7, phys = G & 127;
        int gc = (phys & ~15) | ((phys & 15) ^ (row & 15));
        gload_lds16(h2c + (r0 + row) * HID + gc * 8, &hS[(wave * 256 + i * 64) * 8]);
    }

    int colg[2];
    colg[0] = wave * 32 + ln;
    colg[1] = wave * 32 + 16 + ln;

    // register-resident fragments (pre-converted bf16; plain loads)
    bf16x8 afr[8];
    const int m = wave * 16 + ln;
    const float bvv = b_vec[m];
#pragma unroll
    for (int ks = 0; ks < 8; ++ks)
        afr[ks] = __builtin_bit_cast(bf16x8, *(const uint4*)(AG + m * OUT_DIM + ks * 32 + q * 8));
    float bpv[2];
    bf16x8 wzfr[2][8];
#pragma unroll
    for (int nt = 0; nt < 2; ++nt) {
        bpv[nt] = bp[colg[nt]];
#pragma unroll
        for (int ks = 0; ks < 8; ++ks)
            wzfr[nt][ks] = __builtin_bit_cast(bf16x8, *(const uint4*)(WzG + colg[nt] * OUT_DIM + ks * 32 + q * 8));
    }
    __syncthreads();   // hS ready (barrier drains vmcnt)

    // ---- gemm3: acc3 = h2_slab @ W2c^T; each wave does 32 cols ----
    f32x4 acc3[2];
    acc3[0] = (f32x4){0.f, 0.f, 0.f, 0.f};
    acc3[1] = (f32x4){0.f, 0.f, 0.f, 0.f};
#pragma unroll 4
    for (int ks = 0; ks < 32; ++ks) {
        int gci = ks * 4 + q;
        int phys = (gci & ~15) | ((gci & 15) ^ ln);
        bf16x8 af = __builtin_bit_cast(bf16x8, *(const uint4*)&hS[ln * 1024 + phys * 8]);
#pragma unroll
        for (int nt = 0; nt < 2; ++nt) {
            bf16x8 wf = __builtin_bit_cast(bf16x8, *(const uint4*)(W2c + colg[nt] * HID + ks * 32 + q * 8));
            acc3[nt] = __builtin_amdgcn_mfma_f32_16x16x32_bf16(af, wf, acc3[nt], 0, 0, 0);
        }
    }

    // epilogue: write out0 (f32) and seed zS = bf16(out0)
#pragma unroll
    for (int nt = 0; nt < 2; ++nt) {
        float bv = b2v[colg[nt]];
#pragma unroll
        for (int i = 0; i < 4; ++i) {
            float v = acc3[nt][i] + bv;
            outz[(r0 + q * 4 + i) * OUT_DIM + colg[nt]] = v;
            zS[q * 4 + i][colg[nt]] = f2bf(v);
        }
    }
    __syncthreads();   // zS seed complete

    bf16x8 zfr[8];
#pragma unroll
    for (int ks = 0; ks < 8; ++ks)
        zfr[ks] = __builtin_bit_cast(bf16x8, *(const uint4*)&zS[ln][ks * 32 + q * 8]);

    const f32x4 zero4 = {0.f, 0.f, 0.f, 0.f};

    for (int t = 1; t <= MAX_ITER_N; ++t) {
        f32x4 acc[2];
        acc[0] = zero4; acc[1] = zero4;
        f32x4 acc2 = zero4;
#pragma unroll
        for (int ks = 0; ks < 8; ++ks) {
#pragma unroll
            for (int nt = 0; nt < 2; ++nt)
                acc[nt] = __builtin_amdgcn_mfma_f32_16x16x32_bf16(zfr[ks], wzfr[nt][ks], acc[nt], 0, 0, 0);
            if (t > 1)
                acc2 = __builtin_amdgcn_mfma_f32_16x16x32_bf16(zfr[ks], afr[ks], acc2, 0, 0, 0);
        }
        float vals[2][4];
#pragma unroll
        for (int nt = 0; nt < 2; ++nt)
#pragma unroll
            for (int i = 0; i < 4; ++i) {
                float v = acc[nt][i] + bpv[nt];
                if (colg[nt] >= FREE_NUM_N) v = fmaxf(v, 0.0f);
                vals[nt][i] = v;
            }
        if (t > 1) {   // residual of z_{t-1} -> redL[t-2][wave] (LDS only)
            float lmax = 0.0f;
#pragma unroll
            for (int i = 0; i < 4; ++i)
                lmax = fmaxf(lmax, fabsf(acc2[i] - bvv));
#pragma unroll
            for (int off = 32; off > 0; off >>= 1)
                lmax = fmaxf(lmax, __shfl_xor(lmax, off));
            if (lane == 0) redL[(t - 2) * 8 + wave] = lmax;
        }
        if (t == MAX_ITER_N) {
#pragma unroll
            for (int nt = 0; nt < 2; ++nt)
#pragma unroll
                for (int i = 0; i < 4; ++i)
                    out[(r0 + q * 4 + i) * OUT_DIM + colg[nt]] = vals[nt][i];
        }
        __syncthreads();   // S1: reads of zS done + redL written
#pragma unroll
        for (int nt = 0; nt < 2; ++nt)
#pragma unroll
            for (int i = 0; i < 4; ++i)
                zS[q * 4 + i][colg[nt]] = f2bf(vals[nt][i]);
        __syncthreads();   // S2: zS = z_t complete
#pragma unroll
        for (int ks = 0; ks < 8; ++ks)
            zfr[ks] = __builtin_bit_cast(bf16x8, *(const uint4*)&zS[ln][ks * 32 + q * 8]);
    }

    {   // final residual of z_20 -> redL[19][wave]
        f32x4 acc2 = zero4;
#pragma unroll
        for (int ks = 0; ks < 8; ++ks)
            acc2 = __builtin_amdgcn_mfma_f32_16x16x32_bf16(zfr[ks], afr[ks], acc2, 0, 0, 0);
        float lmax = 0.0f;
#pragma unroll
        for (int i = 0; i < 4; ++i)
            lmax = fmaxf(lmax, fabsf(acc2[i] - bvv));
#pragma unroll
        for (int off = 32; off > 0; off >>= 1)
            lmax = fmaxf(lmax, __shfl_xor(lmax, off));
        if (lane == 0) redL[19 * 8 + wave] = lmax;
    }
    __syncthreads();   // all redL complete

    // ---- flush: 20 parallel atomicMax (once per block, off the loop path) ----
    if (tid < MAX_ITER_N) {
        float rv = redL[tid * 8];
#pragma unroll
        for (int w2 = 1; w2 < 8; ++w2) rv = fmaxf(rv, redL[tid * 8 + w2]);
        atomicMax(res + tid, __float_as_uint(rv));
    }
    __syncthreads();   // wave0's atomics drained (per-wave vmcnt at barrier)

    if (tid == 0) {
        __threadfence();
        atomicAdd(done, 1u);
        while (__hip_atomic_load(done, __ATOMIC_ACQUIRE, __HIP_MEMORY_SCOPE_AGENT) < 64u)
            __builtin_amdgcn_s_sleep(2);
    }
    __syncthreads();   // all 64 blocks' res[] contributions complete

    // ---- decide: replay reference stopping rule ----
    {
        float rv = 1e30f;
        if (tid < MAX_ITER_N)
            rv = __uint_as_float(__hip_atomic_load(res + tid, __ATOMIC_ACQUIRE, __HIP_MEMORY_SCOPE_AGENT));
        if (tid < 64) {
            unsigned long long mm = __ballot((tid < MAX_ITER_N) && !(rv > F_TOL_F));
            if (tid == 0) Tsh = (float)(mm ? (int)__ffsll(mm) : MAX_ITER_N);
        }
        __syncthreads();
    }
    const int T = (int)Tsh;
    if (bid == 0 && tid == 0)
        out[2 * BSZ * OUT_DIM] = (float)(T + 1);    // curr_iter
    if (T >= MAX_ITER_N) return;                    // hot path

    // ---- cold fp32 fallback for this block's 16 rows (hS reused as zF) ----
    {
        float (*zF)[257] = (float(*)[257])hS;
        const int row = tid >> 4;                   // valid for tid < 256
        const int c0 = (tid & 15) * 16;
        if (tid < 256)
            for (int i = 0; i < 16; ++i)
                zF[row][c0 + i] = outz[(r0 + row) * OUT_DIM + c0 + i];
        __syncthreads();
        const int j = tid;
        const float bj = (tid < 256) ? bp[j] : 0.0f;
        for (int t = 0; t < T; ++t) {
            float acc[16] = {};
            if (tid < 256) {
                for (int k = 0; k < OUT_DIM; ++k) {
                    float wv = Wzf[j * OUT_DIM + k];
#pragma unroll
                    for (int r = 0; r < 16; ++r) acc[r] += zF[r][k] * wv;
                }
            }
            __syncthreads();
            if (tid < 256) {
#pragma unroll
                for (int r = 0; r < 16; ++r) {
                    float v = acc[r] + bj;
                    if (j >= FREE_NUM_N) v = fmaxf(v, 0.0f);
                    zF[r][j] = v;
                }
            }
            __syncthreads();
        }
        if (tid < 256)
            for (int i = 0; i < 16; ++i)
                out[(r0 + row) * OUT_DIM + c0 + i] = zF[row][c0 + i];
    }
}

extern "C" void kernel_launch(void* const* d_in, const int* in_sizes, int n_in,
                              void* d_out, int out_size, void* d_ws, size_t ws_size,
                              hipStream_t stream) {
    const float* b_primal = (const float*)d_in[0];
    const float* W0     = (const float*)d_in[1];
    const float* b0     = (const float*)d_in[2];
    const float* W1     = (const float*)d_in[3];
    const float* b1     = (const float*)d_in[4];
    const float* W2     = (const float*)d_in[5];
    const float* b2     = (const float*)d_in[6];
    const float* Amat   = (const float*)d_in[7];
    const float* b_vec  = (const float*)d_in[8];
    const float* WzProj = (const float*)d_in[9];
    const float* WbProj = (const float*)d_in[10];
    float* out = (float*)d_out;
    float* ws  = (float*)d_ws;

    unsigned short* h1c = (unsigned short*)(ws + WS_H1);
    unsigned short* h2c = (unsigned short*)(ws + WS_H2);

    // g1: h1 = relu(x @ W0^T + b0); extra 96 blocks convert W2/Wz/Am + bias_proj + ctrl-zero
    hipLaunchKernelGGL((gemm_k<IN_DIM, true, true>), dim3(352), dim3(256), 0, stream,
                       (const void*)b_primal, W0, b0, h1c, ws,
                       W2, WzProj, Amat, b_vec, WbProj);
    // g2: h2 = relu(h1 @ W1^T + b1)
    hipLaunchKernelGGL((gemm_k<HID, false, true>), dim3(256), dim3(256), 0, stream,
                       (const void*)h1c, W1, b1, h2c, ws,
                       nullptr, nullptr, nullptr, nullptr, nullptr);
    // k3: per-block gemm3 slab + 20-iter loop (no global traffic) + decide + fallback
    hipLaunchKernelGGL(k3_k, dim3(64), dim3(512), 0, stream,
                       b2, b_vec, WzProj, out, ws);
}

// Round 6
// 140.446 us; speedup vs baseline: 2.3098x; 1.0114x over previous
//
#include <hip/hip_runtime.h>

typedef __attribute__((ext_vector_type(8))) __bf16 bf16x8;
typedef __attribute__((ext_vector_type(4))) float f32x4;

#define MAX_ITER_N 20
#define F_TOL_F 1e-6f
#define FREE_NUM_N 64

#define BSZ 1024
#define IN_DIM 512
#define HID 1024
#define OUT_DIM 256
#define M_CON 128

// workspace layout (float offsets); ctrl region [0..48) zeroed by g1 extra block
#define WS_DONE  0                         // uint: loop completion counter
#define WS_RES   8                         // 32 uints: per-iter residuals
#define WS_BP    48                        // 256 f32: bias_proj
#define WS_H1    304                       // h1 bf16 [1024][1024]
#define WS_H2    (WS_H1 + 524288)          // h2 bf16 [1024][1024]
#define WS_W2C   (WS_H2 + 524288)          // W2 bf16 [256][1024]
#define WS_WZG   (WS_W2C + 131072)         // Wz bf16 [256][256]
#define WS_AG    (WS_WZG + 32768)          // A  bf16 [128][256]

__device__ __forceinline__ unsigned short f2bf(float f) {
    unsigned int u = __float_as_uint(f);
    u += 0x7fffu + ((u >> 16) & 1u);
    return (unsigned short)(u >> 16);
}

__device__ __forceinline__ unsigned int pk2(float a, float b) {
    return (unsigned int)f2bf(a) | ((unsigned int)f2bf(b) << 16);
}

__device__ __forceinline__ void cvt16(const float* s, unsigned short* d) {
    float4 v0 = *(const float4*)s,       v1 = *(const float4*)(s + 4),
           v2 = *(const float4*)(s + 8), v3 = *(const float4*)(s + 12);
    *(uint4*)d       = (uint4){pk2(v0.x, v0.y), pk2(v0.z, v0.w), pk2(v1.x, v1.y), pk2(v1.z, v1.w)};
    *(uint4*)(d + 8) = (uint4){pk2(v2.x, v2.y), pk2(v2.z, v2.w), pk2(v3.x, v3.y), pk2(v3.z, v3.w)};
}

__device__ __forceinline__ void gload_lds16(const unsigned short* g, unsigned short* l) {
    __builtin_amdgcn_global_load_lds(
        (const __attribute__((address_space(1))) unsigned int*)(const void*)g,
        (__attribute__((address_space(3))) unsigned int*)(void*)l, 16, 0, 0);
}

// fragment read from a 64x128 bf16 LDS tile with 4-bit XOR granule swizzle
__device__ __forceinline__ bf16x8 frag128(const unsigned short* lds, int row, int gc) {
    int phys = gc ^ (row & 15);
    return __builtin_bit_cast(bf16x8, *(const uint4*)(lds + row * 128 + phys * 8));
}

// ---- 64x64-tile MFMA GEMM kernel, BK=128, double-buffered LDS ----
// C[1024][1024] bf16 = act(A[1024][K] @ B[1024][K]^T + bias)
// AF32 (g1): A is f32 (inline convert, reg-staged); extra blocks (>=256) do
// weight conversions + bias_proj + ctrl-zero in parallel with the GEMM.
template<int K, bool AF32, bool RELU>
__global__ __launch_bounds__(256) void gemm_k(
    const void* __restrict__ Ap, const float* __restrict__ Bf,
    const float* __restrict__ bias, unsigned short* __restrict__ C,
    float* __restrict__ ws,
    const float* __restrict__ W2, const float* __restrict__ Wz,
    const float* __restrict__ Am, const float* __restrict__ b_vec,
    const float* __restrict__ WbP)
{
    constexpr int NCH = K / 128;
    __shared__ __align__(16) unsigned short sA[2][8192];
    __shared__ __align__(16) unsigned short sB[2][8192];

    const int tid = threadIdx.x;

    if constexpr (AF32) {
        if (blockIdx.x >= 256) {            // side work, overlapped with GEMM
            int eb = blockIdx.x - 256;
            unsigned short* W2c = (unsigned short*)(ws + WS_W2C);
            unsigned short* WzG = (unsigned short*)(ws + WS_WZG);
            unsigned short* AG  = (unsigned short*)(ws + WS_AG);
            float* bp = ws + WS_BP;
            if (eb < 64) {                  // W2: 262144 floats -> bf16
                int base = eb * 4096 + tid * 16;
                cvt16(W2 + base, W2c + base);
            } else if (eb < 80) {           // Wz: 65536 floats
                int base = (eb - 64) * 4096 + tid * 16;
                cvt16(Wz + base, WzG + base);
            } else if (eb < 88) {           // Am: 32768 floats
                int base = (eb - 80) * 4096 + tid * 16;
                cvt16(Am + base, AG + base);
            } else {                        // 8 blocks: bias_proj, coalesced
                if (eb == 88 && tid < 48) ((unsigned int*)ws)[tid] = 0u;
                int j  = (eb - 88) * 32 + (tid >> 3);
                int kg = tid & 7;
                const float* p = WbP + j * M_CON + kg * 16;
                float s = 0.0f;
#pragma unroll
                for (int i = 0; i < 16; ++i) s += p[i] * b_vec[kg * 16 + i];
#pragma unroll
                for (int off = 4; off > 0; off >>= 1) s += __shfl_xor(s, off);
                if (kg == 0) bp[j] = s;
            }
            return;
        }
    }

    const int w = tid >> 6;
    const int lane = tid & 63;
    const int ln = lane & 15;
    const int q  = lane >> 4;
    const int wr = w >> 1;
    const int wc = w & 1;
    const int row0 = (blockIdx.x >> 4) * 64;
    const int col0 = (blockIdx.x & 15) * 64;

    // reg-staging geometry: granule P = tid + 256*i; row=P>>4, gc=P&15
    int grow[4], ggc[4], lof[4];
#pragma unroll
    for (int i = 0; i < 4; ++i) {
        int P = tid + 256 * i;
        grow[i] = P >> 4; ggc[i] = P & 15;
        lof[i] = grow[i] * 128 + (ggc[i] ^ (grow[i] & 15)) * 8;
    }
    // A-bf16 gload_lds geometry (pre-swizzled source, lane-linear dest)
    int soff[4], dbase[4];
    const unsigned short* Ab_h = (const unsigned short*)Ap + row0 * K;
    const float*          Ab_f = (const float*)Ap + row0 * K;
    if constexpr (!AF32) {
#pragma unroll
        for (int i = 0; i < 4; ++i) {
            int P = w * 256 + i * 64 + lane;
            int row = P >> 4, pgc = P & 15;
            soff[i]  = row * K + (pgc ^ (row & 15)) * 8;
            dbase[i] = (w * 256 + i * 64) * 8;
        }
    }
    const float* Bb = Bf + col0 * K;

    float4 ra[8], rb[8];

    // ---- prologue: stage chunk 0 into buffer 0 ----
    if constexpr (AF32) {
#pragma unroll
        for (int i = 0; i < 4; ++i) {
            const float* s = Ab_f + grow[i] * K + ggc[i] * 8;
            ra[2*i]   = *(const float4*)s;
            ra[2*i+1] = *(const float4*)(s + 4);
        }
    } else {
#pragma unroll
        for (int i = 0; i < 4; ++i) gload_lds16(Ab_h + soff[i], &sA[0][dbase[i]]);
    }
#pragma unroll
    for (int i = 0; i < 4; ++i) {
        const float* s = Bb + grow[i] * K + ggc[i] * 8;
        rb[2*i]   = *(const float4*)s;
        rb[2*i+1] = *(const float4*)(s + 4);
    }
    if constexpr (AF32) {
#pragma unroll
        for (int i = 0; i < 4; ++i)
            *(uint4*)(&sA[0][lof[i]]) = (uint4){
                pk2(ra[2*i].x, ra[2*i].y),   pk2(ra[2*i].z, ra[2*i].w),
                pk2(ra[2*i+1].x, ra[2*i+1].y), pk2(ra[2*i+1].z, ra[2*i+1].w)};
    }
#pragma unroll
    for (int i = 0; i < 4; ++i)
        *(uint4*)(&sB[0][lof[i]]) = (uint4){
            pk2(rb[2*i].x, rb[2*i].y),   pk2(rb[2*i].z, rb[2*i].w),
            pk2(rb[2*i+1].x, rb[2*i+1].y), pk2(rb[2*i+1].z, rb[2*i+1].w)};

    f32x4 acc[2][2];
#pragma unroll
    for (int rm = 0; rm < 2; ++rm)
#pragma unroll
        for (int cn = 0; cn < 2; ++cn)
            acc[rm][cn] = (f32x4){0.f, 0.f, 0.f, 0.f};

    for (int c = 0; c < NCH; ++c) {
        __syncthreads();                     // buf[c&1] staging complete
        const int nb = (c + 1) & 1;
        if (c + 1 < NCH) {                   // issue next-chunk loads (hide under MFMA)
            const int koff = (c + 1) * 128;
            if constexpr (AF32) {
#pragma unroll
                for (int i = 0; i < 4; ++i) {
                    const float* s = Ab_f + grow[i] * K + koff + ggc[i] * 8;
                    ra[2*i]   = *(const float4*)s;
                    ra[2*i+1] = *(const float4*)(s + 4);
                }
            } else {
#pragma unroll
                for (int i = 0; i < 4; ++i)
                    gload_lds16(Ab_h + koff + soff[i], &sA[nb][dbase[i]]);
            }
#pragma unroll
            for (int i = 0; i < 4; ++i) {
                const float* s = Bb + grow[i] * K + koff + ggc[i] * 8;
                rb[2*i]   = *(const float4*)s;
                rb[2*i+1] = *(const float4*)(s + 4);
            }
        }
        const unsigned short* Ac = sA[c & 1];
        const unsigned short* Bc = sB[c & 1];
#pragma unroll
        for (int ks = 0; ks < 4; ++ks) {
            bf16x8 af0 = frag128(Ac, wr * 32 + ln,      ks * 4 + q);
            bf16x8 af1 = frag128(Ac, wr * 32 + 16 + ln, ks * 4 + q);
            bf16x8 bf0 = frag128(Bc, wc * 32 + ln,      ks * 4 + q);
            bf16x8 bf1 = frag128(Bc, wc * 32 + 16 + ln, ks * 4 + q);
            acc[0][0] = __builtin_amdgcn_mfma_f32_16x16x32_bf16(af0, bf0, acc[0][0], 0, 0, 0);
            acc[0][1] = __builtin_amdgcn_mfma_f32_16x16x32_bf16(af0, bf1, acc[0][1], 0, 0, 0);
            acc[1][0] = __builtin_amdgcn_mfma_f32_16x16x32_bf16(af1, bf0, acc[1][0], 0, 0, 0);
            acc[1][1] = __builtin_amdgcn_mfma_f32_16x16x32_bf16(af1, bf1, acc[1][1], 0, 0, 0);
        }
        if (c + 1 < NCH) {                   // cvt + write staged regs → buf nb
            if constexpr (AF32) {
#pragma unroll
                for (int i = 0; i < 4; ++i)
                    *(uint4*)(&sA[nb][lof[i]]) = (uint4){
                        pk2(ra[2*i].x, ra[2*i].y),   pk2(ra[2*i].z, ra[2*i].w),
                        pk2(ra[2*i+1].x, ra[2*i+1].y), pk2(ra[2*i+1].z, ra[2*i+1].w)};
            }
#pragma unroll
            for (int i = 0; i < 4; ++i)
                *(uint4*)(&sB[nb][lof[i]]) = (uint4){
                    pk2(rb[2*i].x, rb[2*i].y),   pk2(rb[2*i].z, rb[2*i].w),
                    pk2(rb[2*i+1].x, rb[2*i+1].y), pk2(rb[2*i+1].z, rb[2*i+1].w)};
        }
    }

#pragma unroll
    for (int cn = 0; cn < 2; ++cn) {
        const int cc = col0 + wc * 32 + cn * 16 + ln;
        const float bv = bias[cc];
#pragma unroll
        for (int rm = 0; rm < 2; ++rm)
#pragma unroll
            for (int i = 0; i < 4; ++i) {
                int r = row0 + wr * 32 + rm * 16 + q * 4 + i;
                float v = acc[rm][cn][i] + bv;
                if (RELU) v = fmaxf(v, 0.0f);
                C[r * HID + cc] = f2bf(v);
            }
    }
}

// ---- K3: per-block gemm3 slab + 20-iter loop + decide + fallback ----
// 64 blocks x 512 threads (8 waves, 2/SIMD). Loop: double-buffered zS,
// ONE barrier per iteration; all MFMA chains depth-4 (issue-bound, not
// latency-bound); zero global traffic in loop body.
__global__ __launch_bounds__(512, 1) void k3_k(
    const float* __restrict__ b2v, const float* __restrict__ b_vec,
    const float* __restrict__ Wzf, float* __restrict__ out,
    float* __restrict__ ws)
{
    __shared__ __align__(16) unsigned short hS[16 * 1024];  // swizzled h2 slab (reused as zF)
    __shared__ __align__(16) unsigned short zS[2][16][264]; // double-buffered z
    __shared__ float redL[MAX_ITER_N * 8];                  // [ri][wave]
    __shared__ float Tsh;

    unsigned int* done = (unsigned int*)ws;
    unsigned int* res  = (unsigned int*)(ws + WS_RES);
    const float* bp = ws + WS_BP;
    const unsigned short* h2c = (const unsigned short*)(ws + WS_H2);
    const unsigned short* W2c = (const unsigned short*)(ws + WS_W2C);
    const unsigned short* WzG = (const unsigned short*)(ws + WS_WZG);
    const unsigned short* AG  = (const unsigned short*)(ws + WS_AG);
    float* outz = out + BSZ * OUT_DIM;

    const int tid  = threadIdx.x;
    const int wave = tid >> 6;
    const int lane = tid & 63;
    const int ln   = lane & 15;
    const int q    = lane >> 4;
    const int bid  = blockIdx.x;
    const int r0   = bid * 16;

    // stage h2[r0:r0+16][0:1024] -> hS (swizzled): 2048 granules / 8 waves
#pragma unroll
    for (int i = 0; i < 4; ++i) {
        int G = wave * 256 + i * 64 + lane;          // granule (lane-linear dest)
        int row = G >> 7, phys = G & 127;
        int gc = (phys & ~15) | ((phys & 15) ^ (row & 15));
        gload_lds16(h2c + (r0 + row) * HID + gc * 8, &hS[(wave * 256 + i * 64) * 8]);
    }

    int colg[2];
    colg[0] = wave * 32 + ln;
    colg[1] = wave * 32 + 16 + ln;
    const bool relu0 = (wave * 32) >= FREE_NUM_N;         // wave-uniform
    const bool relu1 = (wave * 32 + 16) >= FREE_NUM_N;

    // register-resident fragments (pre-converted bf16; plain loads)
    bf16x8 afr[8];
    const int m = wave * 16 + ln;
    const float bvv = b_vec[m];
#pragma unroll
    for (int ks = 0; ks < 8; ++ks)
        afr[ks] = __builtin_bit_cast(bf16x8, *(const uint4*)(AG + m * OUT_DIM + ks * 32 + q * 8));
    float bpv[2];
    bf16x8 wzfr[2][8];
#pragma unroll
    for (int nt = 0; nt < 2; ++nt) {
        bpv[nt] = bp[colg[nt]];
#pragma unroll
        for (int ks = 0; ks < 8; ++ks)
            wzfr[nt][ks] = __builtin_bit_cast(bf16x8, *(const uint4*)(WzG + colg[nt] * OUT_DIM + ks * 32 + q * 8));
    }
    __syncthreads();   // hS ready (barrier drains vmcnt)

    const f32x4 zero4 = {0.f, 0.f, 0.f, 0.f};

    // ---- gemm3: acc3 = h2_slab @ W2c^T; 4 independent chains of 16 ----
    f32x4 a3a[2], a3b[2];
    a3a[0] = zero4; a3a[1] = zero4; a3b[0] = zero4; a3b[1] = zero4;
#pragma unroll 4
    for (int ks = 0; ks < 16; ++ks) {
        int gciA = ks * 4 + q;
        int physA = (gciA & ~15) | ((gciA & 15) ^ ln);
        bf16x8 afA = __builtin_bit_cast(bf16x8, *(const uint4*)&hS[ln * 1024 + physA * 8]);
        int gciB = (ks + 16) * 4 + q;
        int physB = (gciB & ~15) | ((gciB & 15) ^ ln);
        bf16x8 afB = __builtin_bit_cast(bf16x8, *(const uint4*)&hS[ln * 1024 + physB * 8]);
#pragma unroll
        for (int nt = 0; nt < 2; ++nt) {
            bf16x8 wfA = __builtin_bit_cast(bf16x8, *(const uint4*)(W2c + colg[nt] * HID + ks * 32 + q * 8));
            bf16x8 wfB = __builtin_bit_cast(bf16x8, *(const uint4*)(W2c + colg[nt] * HID + (ks + 16) * 32 + q * 8));
            a3a[nt] = __builtin_amdgcn_mfma_f32_16x16x32_bf16(afA, wfA, a3a[nt], 0, 0, 0);
            a3b[nt] = __builtin_amdgcn_mfma_f32_16x16x32_bf16(afB, wfB, a3b[nt], 0, 0, 0);
        }
    }

    // epilogue: write out0 (f32) and seed zS[0] = bf16(out0)
#pragma unroll
    for (int nt = 0; nt < 2; ++nt) {
        float bv = b2v[colg[nt]];
#pragma unroll
        for (int i = 0; i < 4; ++i) {
            float v = a3a[nt][i] + a3b[nt][i] + bv;
            outz[(r0 + q * 4 + i) * OUT_DIM + colg[nt]] = v;
            zS[0][q * 4 + i][colg[nt]] = f2bf(v);
        }
    }
    __syncthreads();   // zS[0] seed complete

    bf16x8 zfr[8];
#pragma unroll
    for (int ks = 0; ks < 8; ++ks)
        zfr[ks] = __builtin_bit_cast(bf16x8, *(const uint4*)&zS[0][ln][ks * 32 + q * 8]);

    int wb = 1;        // buffer to write this iteration

    for (int t = 1; t <= MAX_ITER_N; ++t) {
        // 4 chains of 4 for z@Wz^T; 2 chains of 4 for residual (t>1)
        f32x4 aA[2], aB[2], r2a, r2b;
        aA[0] = zero4; aA[1] = zero4; aB[0] = zero4; aB[1] = zero4;
        r2a = zero4; r2b = zero4;
#pragma unroll
        for (int ks = 0; ks < 4; ++ks) {
#pragma unroll
            for (int nt = 0; nt < 2; ++nt) {
                aA[nt] = __builtin_amdgcn_mfma_f32_16x16x32_bf16(zfr[ks],     wzfr[nt][ks],     aA[nt], 0, 0, 0);
                aB[nt] = __builtin_amdgcn_mfma_f32_16x16x32_bf16(zfr[ks + 4], wzfr[nt][ks + 4], aB[nt], 0, 0, 0);
            }
            if (t > 1) {
                r2a = __builtin_amdgcn_mfma_f32_16x16x32_bf16(zfr[ks],     afr[ks],     r2a, 0, 0, 0);
                r2b = __builtin_amdgcn_mfma_f32_16x16x32_bf16(zfr[ks + 4], afr[ks + 4], r2b, 0, 0, 0);
            }
        }
        float vals[2][4];
#pragma unroll
        for (int nt = 0; nt < 2; ++nt) {
            const bool rl = nt ? relu1 : relu0;
#pragma unroll
            for (int i = 0; i < 4; ++i) {
                float v = aA[nt][i] + aB[nt][i] + bpv[nt];
                if (rl) v = fmaxf(v, 0.0f);
                vals[nt][i] = v;
            }
        }
        if (t > 1) {   // residual of z_{t-1} -> redL[t-2][wave] (LDS only)
            float lmax = 0.0f;
#pragma unroll
            for (int i = 0; i < 4; ++i)
                lmax = fmaxf(lmax, fabsf(r2a[i] + r2b[i] - bvv));
#pragma unroll
            for (int off = 32; off > 0; off >>= 1)
                lmax = fmaxf(lmax, __shfl_xor(lmax, off));
            if (lane == 0) redL[(t - 2) * 8 + wave] = lmax;
        }
        if (t == MAX_ITER_N) {
#pragma unroll
            for (int nt = 0; nt < 2; ++nt)
#pragma unroll
                for (int i = 0; i < 4; ++i)
                    out[(r0 + q * 4 + i) * OUT_DIM + colg[nt]] = vals[nt][i];
        }
        // write z_t into the other buffer (no WAR: reads of buf wb^1 already done)
#pragma unroll
        for (int nt = 0; nt < 2; ++nt)
#pragma unroll
            for (int i = 0; i < 4; ++i)
                zS[wb][q * 4 + i][colg[nt]] = f2bf(vals[nt][i]);
        __syncthreads();   // single barrier: z_t visible to all waves
#pragma unroll
        for (int ks = 0; ks < 8; ++ks)
            zfr[ks] = __builtin_bit_cast(bf16x8, *(const uint4*)&zS[wb][ln][ks * 32 + q * 8]);
        wb ^= 1;
    }

    {   // final residual of z_20 -> redL[19][wave]
        f32x4 r2a = zero4, r2b = zero4;
#pragma unroll
        for (int ks = 0; ks < 4; ++ks) {
            r2a = __builtin_amdgcn_mfma_f32_16x16x32_bf16(zfr[ks],     afr[ks],     r2a, 0, 0, 0);
            r2b = __builtin_amdgcn_mfma_f32_16x16x32_bf16(zfr[ks + 4], afr[ks + 4], r2b, 0, 0, 0);
        }
        float lmax = 0.0f;
#pragma unroll
        for (int i = 0; i < 4; ++i)
            lmax = fmaxf(lmax, fabsf(r2a[i] + r2b[i] - bvv));
#pragma unroll
        for (int off = 32; off > 0; off >>= 1)
            lmax = fmaxf(lmax, __shfl_xor(lmax, off));
        if (lane == 0) redL[19 * 8 + wave] = lmax;
    }
    __syncthreads();   // all redL complete

    // ---- flush: 20 parallel atomicMax (once per block, off the loop path) ----
    if (tid < MAX_ITER_N) {
        float rv = redL[tid * 8];
#pragma unroll
        for (int w2 = 1; w2 < 8; ++w2) rv = fmaxf(rv, redL[tid * 8 + w2]);
        atomicMax(res + tid, __float_as_uint(rv));
    }
    __syncthreads();   // wave0's atomics drained (per-wave vmcnt at barrier)

    if (tid == 0) {
        __threadfence();
        atomicAdd(done, 1u);
        while (__hip_atomic_load(done, __ATOMIC_ACQUIRE, __HIP_MEMORY_SCOPE_AGENT) < 64u)
            __builtin_amdgcn_s_sleep(2);
    }
    __syncthreads();   // all 64 blocks' res[] contributions complete

    // ---- decide: replay reference stopping rule ----
    {
        float rv = 1e30f;
        if (tid < MAX_ITER_N)
            rv = __uint_as_float(__hip_atomic_load(res + tid, __ATOMIC_ACQUIRE, __HIP_MEMORY_SCOPE_AGENT));
        if (tid < 64) {
            unsigned long long mm = __ballot((tid < MAX_ITER_N) && !(rv > F_TOL_F));
            if (tid == 0) Tsh = (float)(mm ? (int)__ffsll(mm) : MAX_ITER_N);
        }
        __syncthreads();
    }
    const int T = (int)Tsh;
    if (bid == 0 && tid == 0)
        out[2 * BSZ * OUT_DIM] = (float)(T + 1);    // curr_iter
    if (T >= MAX_ITER_N) return;                    // hot path

    // ---- cold fp32 fallback for this block's 16 rows (hS reused as zF) ----
    {
        float (*zF)[257] = (float(*)[257])hS;
        const int row = tid >> 4;                   // valid for tid < 256
        const int c0 = (tid & 15) * 16;
        if (tid < 256)
            for (int i = 0; i < 16; ++i)
                zF[row][c0 + i] = outz[(r0 + row) * OUT_DIM + c0 + i];
        __syncthreads();
        const int j = tid;
        const float bj = (tid < 256) ? bp[j] : 0.0f;
        for (int t = 0; t < T; ++t) {
            float acc[16] = {};
            if (tid < 256) {
                for (int k = 0; k < OUT_DIM; ++k) {
                    float wv = Wzf[j * OUT_DIM + k];
#pragma unroll
                    for (int r = 0; r < 16; ++r) acc[r] += zF[r][k] * wv;
                }
            }
            __syncthreads();
            if (tid < 256) {
#pragma unroll
                for (int r = 0; r < 16; ++r) {
                    float v = acc[r] + bj;
                    if (j >= FREE_NUM_N) v = fmaxf(v, 0.0f);
                    zF[r][j] = v;
                }
            }
            __syncthreads();
        }
        if (tid < 256)
            for (int i = 0; i < 16; ++i)
                out[(r0 + row) * OUT_DIM + c0 + i] = zF[row][c0 + i];
    }
}

extern "C" void kernel_launch(void* const* d_in, const int* in_sizes, int n_in,
                              void* d_out, int out_size, void* d_ws, size_t ws_size,
                              hipStream_t stream) {
    const float* b_primal = (const float*)d_in[0];
    const float* W0     = (const float*)d_in[1];
    const float* b0     = (const float*)d_in[2];
    const float* W1     = (const float*)d_in[3];
    const float* b1     = (const float*)d_in[4];
    const float* W2     = (const float*)d_in[5];
    const float* b2     = (const float*)d_in[6];
    const float* Amat   = (const float*)d_in[7];
    const float* b_vec  = (const float*)d_in[8];
    const float* WzProj = (const float*)d_in[9];
    const float* WbProj = (const float*)d_in[10];
    float* out = (float*)d_out;
    float* ws  = (float*)d_ws;

    unsigned short* h1c = (unsigned short*)(ws + WS_H1);
    unsigned short* h2c = (unsigned short*)(ws + WS_H2);

    // g1: h1 = relu(x @ W0^T + b0); extra 96 blocks convert W2/Wz/Am + bias_proj + ctrl-zero
    hipLaunchKernelGGL((gemm_k<IN_DIM, true, true>), dim3(352), dim3(256), 0, stream,
                       (const void*)b_primal, W0, b0, h1c, ws,
                       W2, WzProj, Amat, b_vec, WbProj);
    // g2: h2 = relu(h1 @ W1^T + b1)
    hipLaunchKernelGGL((gemm_k<HID, false, true>), dim3(256), dim3(256), 0, stream,
                       (const void*)h1c, W1, b1, h2c, ws,
                       nullptr, nullptr, nullptr, nullptr, nullptr);
    // k3: per-block gemm3 slab + 20-iter loop (single-barrier dbuf) + decide + fallback
    hipLaunchKernelGGL(k3_k, dim3(64), dim3(512), 0, stream,
                       b2, b_vec, WzProj, out, ws);
}

// Round 7
// 137.574 us; speedup vs baseline: 2.3580x; 1.0209x over previous
//
#include <hip/hip_runtime.h>

typedef __attribute__((ext_vector_type(8))) __bf16 bf16x8;
typedef __attribute__((ext_vector_type(4))) float f32x4;

#define MAX_ITER_N 20
#define F_TOL_F 1e-6f
#define FREE_NUM_N 64

#define BSZ 1024
#define IN_DIM 512
#define HID 1024
#define OUT_DIM 256
#define M_CON 128

// workspace layout (float offsets); ctrl region [0..48) zeroed by g1 extra block
#define WS_DONE  0                         // uint: loop completion counter
#define WS_RES   8                         // 32 uints: per-iter residuals
#define WS_BP    48                        // 256 f32: bias_proj
#define WS_H1    304                       // h1 bf16 [1024][1024]
#define WS_H2    (WS_H1 + 524288)          // h2 bf16 [1024][1024]
#define WS_W2C   (WS_H2 + 524288)          // W2 bf16 [256][1024]
#define WS_WZG   (WS_W2C + 131072)         // Wz bf16 [256][256]
#define WS_AG    (WS_WZG + 32768)          // A  bf16 [128][256]

__device__ __forceinline__ unsigned short f2bf(float f) {
    unsigned int u = __float_as_uint(f);
    u += 0x7fffu + ((u >> 16) & 1u);
    return (unsigned short)(u >> 16);
}

__device__ __forceinline__ unsigned int pk2(float a, float b) {
    return (unsigned int)f2bf(a) | ((unsigned int)f2bf(b) << 16);
}

__device__ __forceinline__ void cvt16(const float* s, unsigned short* d) {
    float4 v0 = *(const float4*)s,       v1 = *(const float4*)(s + 4),
           v2 = *(const float4*)(s + 8), v3 = *(const float4*)(s + 12);
    *(uint4*)d       = (uint4){pk2(v0.x, v0.y), pk2(v0.z, v0.w), pk2(v1.x, v1.y), pk2(v1.z, v1.w)};
    *(uint4*)(d + 8) = (uint4){pk2(v2.x, v2.y), pk2(v2.z, v2.w), pk2(v3.x, v3.y), pk2(v3.z, v3.w)};
}

__device__ __forceinline__ void gload_lds16(const unsigned short* g, unsigned short* l) {
    __builtin_amdgcn_global_load_lds(
        (const __attribute__((address_space(1))) unsigned int*)(const void*)g,
        (__attribute__((address_space(3))) unsigned int*)(void*)l, 16, 0, 0);
}

// fragment read from a 64x128 bf16 LDS tile with 4-bit XOR granule swizzle
__device__ __forceinline__ bf16x8 frag128(const unsigned short* lds, int row, int gc) {
    int phys = gc ^ (row & 15);
    return __builtin_bit_cast(bf16x8, *(const uint4*)(lds + row * 128 + phys * 8));
}

// ---- 64x64-tile MFMA GEMM kernel, BK=128, double-buffered LDS ----
// C[1024][1024] bf16 = act(A[1024][K] @ B[1024][K]^T + bias)
// AF32 (g1): A is f32 (inline convert, reg-staged); extra blocks (>=256) do
// weight conversions + bias_proj + ctrl-zero in parallel with the GEMM.
template<int K, bool AF32, bool RELU>
__global__ __launch_bounds__(256) void gemm_k(
    const void* __restrict__ Ap, const float* __restrict__ Bf,
    const float* __restrict__ bias, unsigned short* __restrict__ C,
    float* __restrict__ ws,
    const float* __restrict__ W2, const float* __restrict__ Wz,
    const float* __restrict__ Am, const float* __restrict__ b_vec,
    const float* __restrict__ WbP)
{
    constexpr int NCH = K / 128;
    __shared__ __align__(16) unsigned short sA[2][8192];
    __shared__ __align__(16) unsigned short sB[2][8192];

    const int tid = threadIdx.x;

    if constexpr (AF32) {
        if (blockIdx.x >= 256) {            // side work, overlapped with GEMM
            int eb = blockIdx.x - 256;
            unsigned short* W2c = (unsigned short*)(ws + WS_W2C);
            unsigned short* WzG = (unsigned short*)(ws + WS_WZG);
            unsigned short* AG  = (unsigned short*)(ws + WS_AG);
            float* bp = ws + WS_BP;
            if (eb < 64) {                  // W2: 262144 floats -> bf16
                int base = eb * 4096 + tid * 16;
                cvt16(W2 + base, W2c + base);
            } else if (eb < 80) {           // Wz: 65536 floats
                int base = (eb - 64) * 4096 + tid * 16;
                cvt16(Wz + base, WzG + base);
            } else if (eb < 88) {           // Am: 32768 floats
                int base = (eb - 80) * 4096 + tid * 16;
                cvt16(Am + base, AG + base);
            } else {                        // 8 blocks: bias_proj, coalesced
                if (eb == 88 && tid < 48) ((unsigned int*)ws)[tid] = 0u;
                int j  = (eb - 88) * 32 + (tid >> 3);
                int kg = tid & 7;
                const float* p = WbP + j * M_CON + kg * 16;
                float s = 0.0f;
#pragma unroll
                for (int i = 0; i < 16; ++i) s += p[i] * b_vec[kg * 16 + i];
#pragma unroll
                for (int off = 4; off > 0; off >>= 1) s += __shfl_xor(s, off);
                if (kg == 0) bp[j] = s;
            }
            return;
        }
    }

    const int w = tid >> 6;
    const int lane = tid & 63;
    const int ln = lane & 15;
    const int q  = lane >> 4;
    const int wr = w >> 1;
    const int wc = w & 1;
    const int row0 = (blockIdx.x >> 4) * 64;
    const int col0 = (blockIdx.x & 15) * 64;

    // reg-staging geometry: granule P = tid + 256*i; row=P>>4, gc=P&15
    int grow[4], ggc[4], lof[4];
#pragma unroll
    for (int i = 0; i < 4; ++i) {
        int P = tid + 256 * i;
        grow[i] = P >> 4; ggc[i] = P & 15;
        lof[i] = grow[i] * 128 + (ggc[i] ^ (grow[i] & 15)) * 8;
    }
    // A-bf16 gload_lds geometry (pre-swizzled source, lane-linear dest)
    int soff[4], dbase[4];
    const unsigned short* Ab_h = (const unsigned short*)Ap + row0 * K;
    const float*          Ab_f = (const float*)Ap + row0 * K;
    if constexpr (!AF32) {
#pragma unroll
        for (int i = 0; i < 4; ++i) {
            int P = w * 256 + i * 64 + lane;
            int row = P >> 4, pgc = P & 15;
            soff[i]  = row * K + (pgc ^ (row & 15)) * 8;
            dbase[i] = (w * 256 + i * 64) * 8;
        }
    }
    const float* Bb = Bf + col0 * K;

    float4 ra[8], rb[8];

    // ---- prologue: stage chunk 0 into buffer 0 ----
    if constexpr (AF32) {
#pragma unroll
        for (int i = 0; i < 4; ++i) {
            const float* s = Ab_f + grow[i] * K + ggc[i] * 8;
            ra[2*i]   = *(const float4*)s;
            ra[2*i+1] = *(const float4*)(s + 4);
        }
    } else {
#pragma unroll
        for (int i = 0; i < 4; ++i) gload_lds16(Ab_h + soff[i], &sA[0][dbase[i]]);
    }
#pragma unroll
    for (int i = 0; i < 4; ++i) {
        const float* s = Bb + grow[i] * K + ggc[i] * 8;
        rb[2*i]   = *(const float4*)s;
        rb[2*i+1] = *(const float4*)(s + 4);
    }
    if constexpr (AF32) {
#pragma unroll
        for (int i = 0; i < 4; ++i)
            *(uint4*)(&sA[0][lof[i]]) = (uint4){
                pk2(ra[2*i].x, ra[2*i].y),   pk2(ra[2*i].z, ra[2*i].w),
                pk2(ra[2*i+1].x, ra[2*i+1].y), pk2(ra[2*i+1].z, ra[2*i+1].w)};
    }
#pragma unroll
    for (int i = 0; i < 4; ++i)
        *(uint4*)(&sB[0][lof[i]]) = (uint4){
            pk2(rb[2*i].x, rb[2*i].y),   pk2(rb[2*i].z, rb[2*i].w),
            pk2(rb[2*i+1].x, rb[2*i+1].y), pk2(rb[2*i+1].z, rb[2*i+1].w)};

    f32x4 acc[2][2];
#pragma unroll
    for (int rm = 0; rm < 2; ++rm)
#pragma unroll
        for (int cn = 0; cn < 2; ++cn)
            acc[rm][cn] = (f32x4){0.f, 0.f, 0.f, 0.f};

    for (int c = 0; c < NCH; ++c) {
        __syncthreads();                     // buf[c&1] staging complete
        const int nb = (c + 1) & 1;
        if (c + 1 < NCH) {                   // issue next-chunk loads (hide under MFMA)
            const int koff = (c + 1) * 128;
            if constexpr (AF32) {
#pragma unroll
                for (int i = 0; i < 4; ++i) {
                    const float* s = Ab_f + grow[i] * K + koff + ggc[i] * 8;
                    ra[2*i]   = *(const float4*)s;
                    ra[2*i+1] = *(const float4*)(s + 4);
                }
            } else {
#pragma unroll
                for (int i = 0; i < 4; ++i)
                    gload_lds16(Ab_h + koff + soff[i], &sA[nb][dbase[i]]);
            }
#pragma unroll
            for (int i = 0; i < 4; ++i) {
                const float* s = Bb + grow[i] * K + koff + ggc[i] * 8;
                rb[2*i]   = *(const float4*)s;
                rb[2*i+1] = *(const float4*)(s + 4);
            }
        }
        const unsigned short* Ac = sA[c & 1];
        const unsigned short* Bc = sB[c & 1];
#pragma unroll
        for (int ks = 0; ks < 4; ++ks) {
            bf16x8 af0 = frag128(Ac, wr * 32 + ln,      ks * 4 + q);
            bf16x8 af1 = frag128(Ac, wr * 32 + 16 + ln, ks * 4 + q);
            bf16x8 bf0 = frag128(Bc, wc * 32 + ln,      ks * 4 + q);
            bf16x8 bf1 = frag128(Bc, wc * 32 + 16 + ln, ks * 4 + q);
            acc[0][0] = __builtin_amdgcn_mfma_f32_16x16x32_bf16(af0, bf0, acc[0][0], 0, 0, 0);
            acc[0][1] = __builtin_amdgcn_mfma_f32_16x16x32_bf16(af0, bf1, acc[0][1], 0, 0, 0);
            acc[1][0] = __builtin_amdgcn_mfma_f32_16x16x32_bf16(af1, bf0, acc[1][0], 0, 0, 0);
            acc[1][1] = __builtin_amdgcn_mfma_f32_16x16x32_bf16(af1, bf1, acc[1][1], 0, 0, 0);
        }
        if (c + 1 < NCH) {                   // cvt + write staged regs → buf nb
            if constexpr (AF32) {
#pragma unroll
                for (int i = 0; i < 4; ++i)
                    *(uint4*)(&sA[nb][lof[i]]) = (uint4){
                        pk2(ra[2*i].x, ra[2*i].y),   pk2(ra[2*i].z, ra[2*i].w),
                        pk2(ra[2*i+1].x, ra[2*i+1].y), pk2(ra[2*i+1].z, ra[2*i+1].w)};
            }
#pragma unroll
            for (int i = 0; i < 4; ++i)
                *(uint4*)(&sB[nb][lof[i]]) = (uint4){
                    pk2(rb[2*i].x, rb[2*i].y),   pk2(rb[2*i].z, rb[2*i].w),
                    pk2(rb[2*i+1].x, rb[2*i+1].y), pk2(rb[2*i+1].z, rb[2*i+1].w)};
        }
    }

#pragma unroll
    for (int cn = 0; cn < 2; ++cn) {
        const int cc = col0 + wc * 32 + cn * 16 + ln;
        const float bv = bias[cc];
#pragma unroll
        for (int rm = 0; rm < 2; ++rm)
#pragma unroll
            for (int i = 0; i < 4; ++i) {
                int r = row0 + wr * 32 + rm * 16 + q * 4 + i;
                float v = acc[rm][cn][i] + bv;
                if (RELU) v = fmaxf(v, 0.0f);
                C[r * HID + cc] = f2bf(v);
            }
    }
}

// ---- K3: per-block gemm3 slab + 20-iter loop + decide + fallback ----
// 64 blocks x 512 threads (8 waves, 2/SIMD). Loop: double-buffered zS,
// one barrier/iter, depth-4 chains, no global traffic in loop body.
// Tail: local-hot shortcut — if this block's OWN residuals all exceed TOL,
// global res (a max over blocks) also does => T=20 => hot path; skip the
// done-spin/decide entirely. Cold path identical to proven r5/r6 structure.
__global__ __launch_bounds__(512, 1) void k3_k(
    const float* __restrict__ b2v, const float* __restrict__ b_vec,
    const float* __restrict__ Wzf, float* __restrict__ out,
    float* __restrict__ ws)
{
    __shared__ __align__(16) unsigned short hS[16 * 1024];  // swizzled h2 slab (reused as zF)
    __shared__ __align__(16) unsigned short zS[2][16][264]; // double-buffered z
    __shared__ float redL[MAX_ITER_N * 8];                  // [ri][wave]
    __shared__ float Tsh;
    __shared__ int hotI;

    unsigned int* done = (unsigned int*)ws;
    unsigned int* res  = (unsigned int*)(ws + WS_RES);
    const float* bp = ws + WS_BP;
    const unsigned short* h2c = (const unsigned short*)(ws + WS_H2);
    const unsigned short* W2c = (const unsigned short*)(ws + WS_W2C);
    const unsigned short* WzG = (const unsigned short*)(ws + WS_WZG);
    const unsigned short* AG  = (const unsigned short*)(ws + WS_AG);
    float* outz = out + BSZ * OUT_DIM;

    const int tid  = threadIdx.x;
    const int wave = tid >> 6;
    const int lane = tid & 63;
    const int ln   = lane & 15;
    const int q    = lane >> 4;
    const int bid  = blockIdx.x;
    const int r0   = bid * 16;

    // stage h2[r0:r0+16][0:1024] -> hS (swizzled): 2048 granules / 8 waves
#pragma unroll
    for (int i = 0; i < 4; ++i) {
        int G = wave * 256 + i * 64 + lane;          // granule (lane-linear dest)
        int row = G >> 7, phys = G & 127;
        int gc = (phys & ~15) | ((phys & 15) ^ (row & 15));
        gload_lds16(h2c + (r0 + row) * HID + gc * 8, &hS[(wave * 256 + i * 64) * 8]);
    }

    int colg[2];
    colg[0] = wave * 32 + ln;
    colg[1] = wave * 32 + 16 + ln;
    const bool relu0 = (wave * 32) >= FREE_NUM_N;         // wave-uniform
    const bool relu1 = (wave * 32 + 16) >= FREE_NUM_N;

    // register-resident fragments (pre-converted bf16; plain loads)
    bf16x8 afr[8];
    const int m = wave * 16 + ln;
    const float bvv = b_vec[m];
#pragma unroll
    for (int ks = 0; ks < 8; ++ks)
        afr[ks] = __builtin_bit_cast(bf16x8, *(const uint4*)(AG + m * OUT_DIM + ks * 32 + q * 8));
    float bpv[2];
    bf16x8 wzfr[2][8];
#pragma unroll
    for (int nt = 0; nt < 2; ++nt) {
        bpv[nt] = bp[colg[nt]];
#pragma unroll
        for (int ks = 0; ks < 8; ++ks)
            wzfr[nt][ks] = __builtin_bit_cast(bf16x8, *(const uint4*)(WzG + colg[nt] * OUT_DIM + ks * 32 + q * 8));
    }
    __syncthreads();   // hS ready (barrier drains vmcnt)

    const f32x4 zero4 = {0.f, 0.f, 0.f, 0.f};

    // ---- gemm3: acc3 = h2_slab @ W2c^T; 4 independent chains of 16 ----
    f32x4 a3a[2], a3b[2];
    a3a[0] = zero4; a3a[1] = zero4; a3b[0] = zero4; a3b[1] = zero4;
#pragma unroll 4
    for (int ks = 0; ks < 16; ++ks) {
        int gciA = ks * 4 + q;
        int physA = (gciA & ~15) | ((gciA & 15) ^ ln);
        bf16x8 afA = __builtin_bit_cast(bf16x8, *(const uint4*)&hS[ln * 1024 + physA * 8]);
        int gciB = (ks + 16) * 4 + q;
        int physB = (gciB & ~15) | ((gciB & 15) ^ ln);
        bf16x8 afB = __builtin_bit_cast(bf16x8, *(const uint4*)&hS[ln * 1024 + physB * 8]);
#pragma unroll
        for (int nt = 0; nt < 2; ++nt) {
            bf16x8 wfA = __builtin_bit_cast(bf16x8, *(const uint4*)(W2c + colg[nt] * HID + ks * 32 + q * 8));
            bf16x8 wfB = __builtin_bit_cast(bf16x8, *(const uint4*)(W2c + colg[nt] * HID + (ks + 16) * 32 + q * 8));
            a3a[nt] = __builtin_amdgcn_mfma_f32_16x16x32_bf16(afA, wfA, a3a[nt], 0, 0, 0);
            a3b[nt] = __builtin_amdgcn_mfma_f32_16x16x32_bf16(afB, wfB, a3b[nt], 0, 0, 0);
        }
    }

    // epilogue: write out0 (f32) and seed zS[0] = bf16(out0)
#pragma unroll
    for (int nt = 0; nt < 2; ++nt) {
        float bv = b2v[colg[nt]];
#pragma unroll
        for (int i = 0; i < 4; ++i) {
            float v = a3a[nt][i] + a3b[nt][i] + bv;
            outz[(r0 + q * 4 + i) * OUT_DIM + colg[nt]] = v;
            zS[0][q * 4 + i][colg[nt]] = f2bf(v);
        }
    }
    __syncthreads();   // zS[0] seed complete

    bf16x8 zfr[8];
#pragma unroll
    for (int ks = 0; ks < 8; ++ks)
        zfr[ks] = __builtin_bit_cast(bf16x8, *(const uint4*)&zS[0][ln][ks * 32 + q * 8]);

    int wb = 1;        // buffer to write this iteration

    for (int t = 1; t <= MAX_ITER_N; ++t) {
        // 4 chains of 4 for z@Wz^T; 2 chains of 4 for residual (t>1)
        f32x4 aA[2], aB[2], r2a, r2b;
        aA[0] = zero4; aA[1] = zero4; aB[0] = zero4; aB[1] = zero4;
        r2a = zero4; r2b = zero4;
#pragma unroll
        for (int ks = 0; ks < 4; ++ks) {
#pragma unroll
            for (int nt = 0; nt < 2; ++nt) {
                aA[nt] = __builtin_amdgcn_mfma_f32_16x16x32_bf16(zfr[ks],     wzfr[nt][ks],     aA[nt], 0, 0, 0);
                aB[nt] = __builtin_amdgcn_mfma_f32_16x16x32_bf16(zfr[ks + 4], wzfr[nt][ks + 4], aB[nt], 0, 0, 0);
            }
            if (t > 1) {
                r2a = __builtin_amdgcn_mfma_f32_16x16x32_bf16(zfr[ks],     afr[ks],     r2a, 0, 0, 0);
                r2b = __builtin_amdgcn_mfma_f32_16x16x32_bf16(zfr[ks + 4], afr[ks + 4], r2b, 0, 0, 0);
            }
        }
        float vals[2][4];
#pragma unroll
        for (int nt = 0; nt < 2; ++nt) {
            const bool rl = nt ? relu1 : relu0;
#pragma unroll
            for (int i = 0; i < 4; ++i) {
                float v = aA[nt][i] + aB[nt][i] + bpv[nt];
                if (rl) v = fmaxf(v, 0.0f);
                vals[nt][i] = v;
            }
        }
        if (t > 1) {   // residual of z_{t-1} -> redL[t-2][wave] (LDS only)
            float lmax = 0.0f;
#pragma unroll
            for (int i = 0; i < 4; ++i)
                lmax = fmaxf(lmax, fabsf(r2a[i] + r2b[i] - bvv));
#pragma unroll
            for (int off = 32; off > 0; off >>= 1)
                lmax = fmaxf(lmax, __shfl_xor(lmax, off));
            if (lane == 0) redL[(t - 2) * 8 + wave] = lmax;
        }
        if (t == MAX_ITER_N) {
#pragma unroll
            for (int nt = 0; nt < 2; ++nt)
#pragma unroll
                for (int i = 0; i < 4; ++i)
                    out[(r0 + q * 4 + i) * OUT_DIM + colg[nt]] = vals[nt][i];
        }
        // write z_t into the other buffer (no WAR: reads of buf wb^1 already done)
#pragma unroll
        for (int nt = 0; nt < 2; ++nt)
#pragma unroll
            for (int i = 0; i < 4; ++i)
                zS[wb][q * 4 + i][colg[nt]] = f2bf(vals[nt][i]);
        __syncthreads();   // single barrier: z_t visible to all waves
#pragma unroll
        for (int ks = 0; ks < 8; ++ks)
            zfr[ks] = __builtin_bit_cast(bf16x8, *(const uint4*)&zS[wb][ln][ks * 32 + q * 8]);
        wb ^= 1;
    }

    {   // final residual of z_20 -> redL[19][wave]
        f32x4 r2a = zero4, r2b = zero4;
#pragma unroll
        for (int ks = 0; ks < 4; ++ks) {
            r2a = __builtin_amdgcn_mfma_f32_16x16x32_bf16(zfr[ks],     afr[ks],     r2a, 0, 0, 0);
            r2b = __builtin_amdgcn_mfma_f32_16x16x32_bf16(zfr[ks + 4], afr[ks + 4], r2b, 0, 0, 0);
        }
        float lmax = 0.0f;
#pragma unroll
        for (int i = 0; i < 4; ++i)
            lmax = fmaxf(lmax, fabsf(r2a[i] + r2b[i] - bvv));
#pragma unroll
        for (int off = 32; off > 0; off >>= 1)
            lmax = fmaxf(lmax, __shfl_xor(lmax, off));
        if (lane == 0) redL[19 * 8 + wave] = lmax;
    }
    __syncthreads();   // all redL complete

    // ---- flush: 20 parallel atomicMax + local-hot test ----
    bool lhot = true;
    if (tid < MAX_ITER_N) {
        float rv = redL[tid * 8];
#pragma unroll
        for (int w2 = 1; w2 < 8; ++w2) rv = fmaxf(rv, redL[tid * 8 + w2]);
        atomicMax(res + tid, __float_as_uint(rv));
        lhot = (rv > F_TOL_F);               // this block's iter-tid residual exceeds tol
    }
    if (tid < 64) {
        unsigned long long mm = __ballot((tid < MAX_ITER_N) && lhot);
        if (tid == 0) hotI = ((mm & 0xFFFFFull) == 0xFFFFFull) ? 1 : 0;
    }
    __syncthreads();   // flush drained (per-wave vmcnt at barrier); hotI visible

    // contribute completion regardless (a cold block elsewhere may wait on us)
    if (tid == 0) {
        __threadfence();
        atomicAdd(done, 1u);
    }

    if (hotI) {        // local-hot => global res[t] >= local > TOL for all t => T=20
        if (bid == 0 && tid == 0)
            out[2 * BSZ * OUT_DIM] = (float)(MAX_ITER_N + 1);   // curr_iter = 21
        return;        // hot path: no spin, no decide, no res reads
    }

    // ---- cold path (unchanged): wait for all blocks, decide, fallback ----
    if (tid == 0) {
        while (__hip_atomic_load(done, __ATOMIC_ACQUIRE, __HIP_MEMORY_SCOPE_AGENT) < 64u)
            __builtin_amdgcn_s_sleep(2);
    }
    __syncthreads();   // all 64 blocks' res[] contributions complete

    {
        float rv = 1e30f;
        if (tid < MAX_ITER_N)
            rv = __uint_as_float(__hip_atomic_load(res + tid, __ATOMIC_ACQUIRE, __HIP_MEMORY_SCOPE_AGENT));
        if (tid < 64) {
            unsigned long long mm = __ballot((tid < MAX_ITER_N) && !(rv > F_TOL_F));
            if (tid == 0) Tsh = (float)(mm ? (int)__ffsll(mm) : MAX_ITER_N);
        }
        __syncthreads();
    }
    const int T = (int)Tsh;
    if (bid == 0 && tid == 0)
        out[2 * BSZ * OUT_DIM] = (float)(T + 1);    // curr_iter
    if (T >= MAX_ITER_N) return;

    // ---- cold fp32 fallback for this block's 16 rows (hS reused as zF) ----
    {
        float (*zF)[257] = (float(*)[257])hS;
        const int row = tid >> 4;                   // valid for tid < 256
        const int c0 = (tid & 15) * 16;
        if (tid < 256)
            for (int i = 0; i < 16; ++i)
                zF[row][c0 + i] = outz[(r0 + row) * OUT_DIM + c0 + i];
        __syncthreads();
        const int j = tid;
        const float bj = (tid < 256) ? bp[j] : 0.0f;
        for (int t = 0; t < T; ++t) {
            float acc[16] = {};
            if (tid < 256) {
                for (int k = 0; k < OUT_DIM; ++k) {
                    float wv = Wzf[j * OUT_DIM + k];
#pragma unroll
                    for (int r = 0; r < 16; ++r) acc[r] += zF[r][k] * wv;
                }
            }
            __syncthreads();
            if (tid < 256) {
#pragma unroll
                for (int r = 0; r < 16; ++r) {
                    float v = acc[r] + bj;
                    if (j >= FREE_NUM_N) v = fmaxf(v, 0.0f);
                    zF[r][j] = v;
                }
            }
            __syncthreads();
        }
        if (tid < 256)
            for (int i = 0; i < 16; ++i)
                out[(r0 + row) * OUT_DIM + c0 + i] = zF[row][c0 + i];
    }
}

extern "C" void kernel_launch(void* const* d_in, const int* in_sizes, int n_in,
                              void* d_out, int out_size, void* d_ws, size_t ws_size,
                              hipStream_t stream) {
    const float* b_primal = (const float*)d_in[0];
    const float* W0     = (const float*)d_in[1];
    const float* b0     = (const float*)d_in[2];
    const float* W1     = (const float*)d_in[3];
    const float* b1     = (const float*)d_in[4];
    const float* W2     = (const float*)d_in[5];
    const float* b2     = (const float*)d_in[6];
    const float* Amat   = (const float*)d_in[7];
    const float* b_vec  = (const float*)d_in[8];
    const float* WzProj = (const float*)d_in[9];
    const float* WbProj = (const float*)d_in[10];
    float* out = (float*)d_out;
    float* ws  = (float*)d_ws;

    unsigned short* h1c = (unsigned short*)(ws + WS_H1);
    unsigned short* h2c = (unsigned short*)(ws + WS_H2);

    // g1: h1 = relu(x @ W0^T + b0); extra 96 blocks convert W2/Wz/Am + bias_proj + ctrl-zero
    hipLaunchKernelGGL((gemm_k<IN_DIM, true, true>), dim3(352), dim3(256), 0, stream,
                       (const void*)b_primal, W0, b0, h1c, ws,
                       W2, WzProj, Amat, b_vec, WbProj);
    // g2: h2 = relu(h1 @ W1^T + b1)
    hipLaunchKernelGGL((gemm_k<HID, false, true>), dim3(256), dim3(256), 0, stream,
                       (const void*)h1c, W1, b1, h2c, ws,
                       nullptr, nullptr, nullptr, nullptr, nullptr);
    // k3: per-block gemm3 slab + 20-iter loop + hot-exit tail
    hipLaunchKernelGGL(k3_k, dim3(64), dim3(512), 0, stream,
                       b2, b_vec, WzProj, out, ws);
}